// Round 1
// baseline (1837.604 us; speedup 1.0000x reference)
//
#include <hip/hip_runtime.h>
#include <math.h>

#define Bn 16
#define Lq 384
#define Hn 12
#define Dm 768
#define DH 64
#define QT 8
#define NEGV (-1e18f)

// ---------------- Age/Agr precompute: Age[h][d] = sum_j Wge[d][h*64+j]*Vg[h*64+j]
__global__ __launch_bounds__(256) void k_prep_age(
    const float* __restrict__ Wge, const float* __restrict__ Wgr,
    const float* __restrict__ Vg, float* __restrict__ Age, float* __restrict__ Agr)
{
  int which = blockIdx.x / Hn;
  int h = blockIdx.x % Hn;
  const float* Wsrc = which ? Wgr : Wge;
  float* dst = which ? Agr : Age;
  __shared__ float vg[DH];
  if (threadIdx.x < DH) vg[threadIdx.x] = Vg[h*DH + threadIdx.x];
  __syncthreads();
  for (int d = threadIdx.x; d < Dm; d += 256) {
    const float* wrow = Wsrc + (size_t)d*Dm + h*DH;
    float s = 0.f;
    #pragma unroll 8
    for (int j = 0; j < DH; ++j) s = fmaf(wrow[j], vg[j], s);
    dst[h*Dm + d] = s;
  }
}

// ---------------- winner map: numpy last-write-wins scatter == atomicMax on l
__global__ void k_win(const int* __restrict__ dp, int* __restrict__ win) {
  int i = blockIdx.x*256 + threadIdx.x;
  if (i >= Bn*Lq) return;
  int b = i / Lq, l = i % Lq;
  int p0 = dp[(size_t)(b*2+0)*Lq + l];
  int p1 = dp[(size_t)(b*2+1)*Lq + l];
  atomicMax(&win[(size_t)b*Lq*Lq + (size_t)p0*Lq + p1], l);
}

// ---------------- g (tanh gate) and rlog (per-head rel logit) per (b,l)
__global__ __launch_bounds__(256) void k_grlog(
    const float* __restrict__ values, const float* __restrict__ relations,
    const int* __restrict__ dp, const int* __restrict__ rel_mask,
    const float* __restrict__ Age, const float* __restrict__ Agr,
    const float* __restrict__ Vr,
    float* __restrict__ g, float* __restrict__ rlog)
{
  int blk = blockIdx.x;
  int b = blk / Lq, l = blk % Lq;
  int tid = threadIdx.x, lane = tid & 63, wave = tid >> 6;
  __shared__ float relrow[Dm], hvrow[Dm];
  __shared__ float part[Hn][4];
  int rm = rel_mask[(size_t)b*Lq + l];
  int idx = dp[(size_t)(b*2)*Lq + l];
  const float* vrow = values + ((size_t)b*Lq + idx)*Dm;
  const float* rrow = relations + ((size_t)b*Lq + l)*Dm;
  for (int d = tid; d < Dm; d += 256) {
    relrow[d] = rm ? 0.f : rrow[d];
    hvrow[d]  = (rm || l == 0) ? 0.f : vrow[d];
  }
  __syncthreads();
  for (int h = 0; h < Hn; ++h) {
    float p = 0.f;
    for (int d = tid; d < Dm; d += 256)
      p = fmaf(hvrow[d], Age[h*Dm + d], fmaf(relrow[d], Agr[h*Dm + d], p));
    #pragma unroll
    for (int o = 32; o > 0; o >>= 1) p += __shfl_xor(p, o);
    if (lane == 0) part[h][wave] = p;
  }
  __syncthreads();
  if (tid < Hn) {
    int h = tid;
    float t = part[h][0] + part[h][1] + part[h][2] + part[h][3];
    g[((size_t)b*Hn + h)*Lq + l] = tanhf(t);
  }
  if (tid >= 64 && tid < 64 + Hn) {
    int h = tid - 64;
    float s = 0.f;
    #pragma unroll 8
    for (int j = 0; j < DH; ++j) s = fmaf(relrow[h*DH + j], Vr[h*DH + j], s);
    rlog[((size_t)b*Hn + h)*Lq + l] = s;
  }
}

// ---------------- f32 tiled GEMM: C[M][768] = alpha * A[M][768] @ W[768][768]
__global__ __launch_bounds__(256) void k_gemm(
    const float* __restrict__ A, const float* __restrict__ W,
    float* __restrict__ C, int M, float alpha)
{
  const int N = Dm, K = Dm;
  __shared__ float As[32][64];   // [k][m]
  __shared__ float Bs[32][64];   // [k][n]
  int mb = M / 64;
  int bm = blockIdx.x % mb;
  int bn = blockIdx.x / mb;
  int m0 = bm*64, n0 = bn*64;
  int tid = threadIdx.x;
  int tx = tid & 15, ty = tid >> 4;
  float acc[4][4] = {};
  for (int k0 = 0; k0 < K; k0 += 32) {
    __syncthreads();
    #pragma unroll
    for (int u = 0; u < 2; ++u) {
      int idx = tid*2 + u;                 // 0..511
      int r = idx >> 3, cq = idx & 7;      // A: 64 rows x 8 float4
      float4 av = *(const float4*)&A[(size_t)(m0+r)*K + k0 + cq*4];
      As[cq*4+0][r] = av.x; As[cq*4+1][r] = av.y;
      As[cq*4+2][r] = av.z; As[cq*4+3][r] = av.w;
      int kr = idx >> 4, nq = idx & 15;    // B: 32 k x 16 float4
      *(float4*)&Bs[kr][nq*4] = *(const float4*)&W[(size_t)(k0+kr)*N + n0 + nq*4];
    }
    __syncthreads();
    #pragma unroll
    for (int kk = 0; kk < 32; ++kk) {
      float4 a  = *(const float4*)&As[kk][ty*4];
      float4 bv = *(const float4*)&Bs[kk][tx*4];
      float av4[4] = {a.x, a.y, a.z, a.w};
      float bv4[4] = {bv.x, bv.y, bv.z, bv.w};
      #pragma unroll
      for (int i = 0; i < 4; ++i)
        #pragma unroll
        for (int j = 0; j < 4; ++j)
          acc[i][j] = fmaf(av4[i], bv4[j], acc[i][j]);
    }
  }
  #pragma unroll
  for (int i = 0; i < 4; ++i) {
    float4 o;
    o.x = acc[i][0]*alpha; o.y = acc[i][1]*alpha;
    o.z = acc[i][2]*alpha; o.w = acc[i][3]*alpha;
    *(float4*)&C[(size_t)(m0+ty*4+i)*N + n0 + tx*4] = o;
  }
}

// ---------------- transpose (B,L,D) -> (B,D,L)
__global__ __launch_bounds__(256) void k_transpose(
    const float* __restrict__ in, float* __restrict__ out)
{
  __shared__ float t[32][33];
  int b = blockIdx.z;
  int l0 = blockIdx.x*32, d0 = blockIdx.y*32;
  int tx = threadIdx.x & 31, ty = threadIdx.x >> 5;   // 32 x 8
  #pragma unroll
  for (int r = 0; r < 4; ++r) {
    int ll = ty + r*8;
    t[ll][tx] = in[((size_t)b*Lq + l0 + ll)*Dm + d0 + tx];
  }
  __syncthreads();
  #pragma unroll
  for (int r = 0; r < 4; ++r) {
    int dl = ty + r*8;
    out[((size_t)b*Dm + d0 + dl)*Lq + l0 + tx] = t[tx][dl];
  }
}

// ---------------- fused attention per (b, 8 q-rows)
__global__ __launch_bounds__(256) void k_attn(
    const float* __restrict__ q, const float* __restrict__ kT,
    const float* __restrict__ v, const int* __restrict__ win,
    const float* __restrict__ g, const float* __restrict__ rlog,
    const int* __restrict__ mask, float* __restrict__ ctxm,
    float* __restrict__ aw_out)
{
  __shared__ float S[QT][Lq];
  __shared__ float Rl[QT][Lq];
  __shared__ float aw[QT][Lq];
  __shared__ float qs[QT][DH];
  __shared__ short Wn1[QT][Lq];
  __shared__ short Wn2[QT][Lq];
  __shared__ unsigned long long mbits[QT][Lq/64];

  int blk = blockIdx.x;
  int b = blk / (Lq/QT);
  int q0 = (blk % (Lq/QT)) * QT;
  int tid = threadIdx.x;
  int lane = tid & 63, wave = tid >> 6;

  const int* maskb = mask + (size_t)b*Lq*Lq;
  const int* winb  = win  + (size_t)b*Lq*Lq;

  // phase 0: zero aw, hoist win row/col + mask bits (h-invariant)
  for (int e = tid; e < QT*Lq; e += 256) ((float*)aw)[e] = 0.f;
  for (int pass = 0; pass < 2; ++pass) {
    int kj = tid + pass*256;
    if (kj < Lq) {
      const int* wc = winb + (size_t)kj*Lq + q0;
      int4 wv0 = *(const int4*)wc;
      int4 wv1 = *(const int4*)(wc + 4);
      int w2arr[8] = {wv0.x, wv0.y, wv0.z, wv0.w, wv1.x, wv1.y, wv1.z, wv1.w};
      #pragma unroll
      for (int qi = 0; qi < QT; ++qi) {
        int i = q0 + qi;
        Wn1[qi][kj] = (short)winb[(size_t)i*Lq + kj];
        Wn2[qi][kj] = (short)w2arr[qi];
        unsigned long long bal = __ballot(maskb[(size_t)i*Lq + kj] != 0);
        if (lane == 0) mbits[qi][kj >> 6] = bal;
      }
    }
  }
  __syncthreads();

  for (int h = 0; h < Hn; ++h) {
    const float* kTh = kT + ((size_t)b*Dm + h*DH)*Lq;
    const float* gh  = g    + ((size_t)b*Hn + h)*Lq;
    const float* rh  = rlog + ((size_t)b*Hn + h)*Lq;
    // q tile
    for (int e = tid; e < QT*DH; e += 256) {
      int qi = e >> 6, d = e & 63;
      qs[qi][d] = q[((size_t)b*Lq + q0 + qi)*Dm + h*DH + d];
    }
    __syncthreads();
    // QK + sparse rel gather
    for (int pass = 0; pass < 2; ++pass) {
      int kj = tid + pass*256;
      if (kj < Lq) {
        float acc[QT];
        #pragma unroll
        for (int qi = 0; qi < QT; ++qi) acc[qi] = 0.f;
        #pragma unroll
        for (int d4 = 0; d4 < DH; d4 += 4) {
          float kv0 = kTh[(size_t)(d4+0)*Lq + kj];
          float kv1 = kTh[(size_t)(d4+1)*Lq + kj];
          float kv2 = kTh[(size_t)(d4+2)*Lq + kj];
          float kv3 = kTh[(size_t)(d4+3)*Lq + kj];
          #pragma unroll
          for (int qi = 0; qi < QT; ++qi) {
            const float4 qv = *(const float4*)&qs[qi][d4];
            acc[qi] = fmaf(qv.x, kv0, fmaf(qv.y, kv1, fmaf(qv.z, kv2, fmaf(qv.w, kv3, acc[qi]))));
          }
        }
        #pragma unroll
        for (int qi = 0; qi < QT; ++qi) {
          int bit = (int)((mbits[qi][kj >> 6] >> (kj & 63)) & 1ull);
          int l1 = Wn1[qi][kj], l2 = Wn2[qi][kj];
          float relv = 0.f;
          if (l1 >= 0) relv += rh[l1];
          if (l2 >= 0) relv += rh[l2];
          aw[qi][kj] += acc[qi];
          S[qi][kj]  = bit ? NEGV : acc[qi];
          Rl[qi][kj] = bit ? NEGV : relv;
        }
      }
    }
    __syncthreads();
    // dual softmax + gate combine (wave handles rows wave, wave+4)
    for (int rr = 0; rr < 2; ++rr) {
      int qi = wave + rr*4;
      float sv[6], rv[6];
      float smax = -3.0e38f, rmax = -3.0e38f;
      #pragma unroll
      for (int u = 0; u < 6; ++u) {
        sv[u] = S[qi][lane + u*64];  smax = fmaxf(smax, sv[u]);
        rv[u] = Rl[qi][lane + u*64]; rmax = fmaxf(rmax, rv[u]);
      }
      #pragma unroll
      for (int o = 32; o > 0; o >>= 1) {
        smax = fmaxf(smax, __shfl_xor(smax, o));
        rmax = fmaxf(rmax, __shfl_xor(rmax, o));
      }
      float ssum = 0.f, rsum = 0.f;
      #pragma unroll
      for (int u = 0; u < 6; ++u) {
        sv[u] = __expf(sv[u] - smax); ssum += sv[u];
        rv[u] = __expf(rv[u] - rmax); rsum += rv[u];
      }
      #pragma unroll
      for (int o = 32; o > 0; o >>= 1) {
        ssum += __shfl_xor(ssum, o);
        rsum += __shfl_xor(rsum, o);
      }
      float si = 1.f/ssum, ri = 1.f/rsum;
      #pragma unroll
      for (int u = 0; u < 6; ++u) {
        int kj = lane + u*64;
        int l1 = Wn1[qi][kj], l2 = Wn2[qi][kj];
        float gv = 0.f;
        if (l1 >= 0) gv += gh[l1];
        if (l2 >= 0) gv += gh[l2];
        S[qi][kj] = (1.f - gv)*(sv[u]*si) + gv*(rv[u]*ri);
      }
    }
    __syncthreads();
    // PV
    {
      int d = tid & 63;
      int qa = tid >> 6;   // 0..3; rows qa and qa+4
      const float* vb = v + (size_t)b*Lq*Dm + h*DH + d;
      float a0 = 0.f, a1 = 0.f;
      for (int kj = 0; kj < Lq; ++kj) {
        float vv = vb[(size_t)kj*Dm];
        a0 = fmaf(S[qa][kj],   vv, a0);
        a1 = fmaf(S[qa+4][kj], vv, a1);
      }
      ctxm[((size_t)b*Lq + q0 + qa    )*Dm + h*DH + d] = a0;
      ctxm[((size_t)b*Lq + q0 + qa + 4)*Dm + h*DH + d] = a1;
    }
    __syncthreads();
  }
  // final attention_weights write: masked -> exact NEG, else sum/12
  for (int e = tid; e < QT*Lq; e += 256) {
    int qi = e / Lq, kj = e % Lq;
    int bit = (int)((mbits[qi][kj >> 6] >> (kj & 63)) & 1ull);
    aw_out[(size_t)b*Lq*Lq + (size_t)(q0+qi)*Lq + kj] =
        bit ? NEGV : ((float*)aw)[e]*(1.f/12.f);
  }
}

extern "C" void kernel_launch(void* const* d_in, const int* in_sizes, int n_in,
                              void* d_out, int out_size, void* d_ws, size_t ws_size,
                              hipStream_t stream) {
  const float* queries   = (const float*)d_in[0];
  const float* keys      = (const float*)d_in[1];
  const float* values    = (const float*)d_in[2];
  const float* relations = (const float*)d_in[3];
  const int*   dp_map    = (const int*)d_in[4];
  const int*   mask      = (const int*)d_in[5];
  const int*   rel_mask  = (const int*)d_in[6];
  const float* Wq  = (const float*)d_in[7];
  const float* Wk  = (const float*)d_in[8];
  const float* Wv  = (const float*)d_in[9];
  const float* Wo  = (const float*)d_in[10];
  const float* Wge = (const float*)d_in[11];
  const float* Wgr = (const float*)d_in[12];
  const float* Vr  = (const float*)d_in[13];
  const float* Vg  = (const float*)d_in[14];

  float* ws = (float*)d_ws;
  const size_t SZ = (size_t)Bn*Lq*Dm;          // 4718592
  float* q    = ws;
  float* k    = ws + SZ;
  float* kT   = ws + 2*SZ;
  float* v    = ws + 3*SZ;
  float* ctxm = ws + 4*SZ;
  int*   win  = (int*)(ws + 5*SZ);
  float* g    = ws + 5*SZ + (size_t)Bn*Lq*Lq;
  float* rlog = g + (size_t)Bn*Hn*Lq;
  float* Age  = rlog + (size_t)Bn*Hn*Lq;
  float* Agr  = Age + (size_t)Hn*Dm;

  float* outp = (float*)d_out;                 // (B,L,D)
  float* awp  = outp + SZ;                     // (B,L,L)

  const int M = Bn*Lq;                         // 6144

  hipMemsetAsync(win, 0xFF, (size_t)Bn*Lq*Lq*sizeof(int), stream);
  k_prep_age<<<2*Hn, 256, 0, stream>>>(Wge, Wgr, Vg, Age, Agr);
  k_win<<<(Bn*Lq + 255)/256, 256, 0, stream>>>(dp_map, win);
  k_grlog<<<Bn*Lq, 256, 0, stream>>>(values, relations, dp_map, rel_mask,
                                     Age, Agr, Vr, g, rlog);
  k_gemm<<<(M/64)*(Dm/64), 256, 0, stream>>>(queries, Wq, q, M, 0.125f);
  k_gemm<<<(M/64)*(Dm/64), 256, 0, stream>>>(keys,    Wk, k, M, 1.f);
  k_gemm<<<(M/64)*(Dm/64), 256, 0, stream>>>(values,  Wv, v, M, 1.f);
  k_transpose<<<dim3(Lq/32, Dm/32, Bn), 256, 0, stream>>>(k, kT);
  k_attn<<<Bn*(Lq/QT), 256, 0, stream>>>(q, kT, v, win, g, rlog, mask, ctxm, awp);
  k_gemm<<<(M/64)*(Dm/64), 256, 0, stream>>>(ctxm, Wo, outp, M, 1.f);
}

// Round 2
// 836.639 us; speedup vs baseline: 2.1964x; 2.1964x over previous
//
#include <hip/hip_runtime.h>
#include <math.h>

#define Bn 16
#define Lq 384
#define Hn 12
#define Dm 768
#define DH 64
#define QT2 16
#define NEGV (-1e18f)

// ---------------- Age/Agr precompute: Age[h][d] = sum_j Wge[d][h*64+j]*Vg[h*64+j]
__global__ __launch_bounds__(256) void k_prep_age(
    const float* __restrict__ Wge, const float* __restrict__ Wgr,
    const float* __restrict__ Vg, float* __restrict__ Age, float* __restrict__ Agr)
{
  int which = blockIdx.x / Hn;
  int h = blockIdx.x % Hn;
  const float* Wsrc = which ? Wgr : Wge;
  float* dst = which ? Agr : Age;
  __shared__ float vg[DH];
  if (threadIdx.x < DH) vg[threadIdx.x] = Vg[h*DH + threadIdx.x];
  __syncthreads();
  for (int d = threadIdx.x; d < Dm; d += 256) {
    const float* wrow = Wsrc + (size_t)d*Dm + h*DH;
    float s = 0.f;
    #pragma unroll 8
    for (int j = 0; j < DH; ++j) s = fmaf(wrow[j], vg[j], s);
    dst[h*Dm + d] = s;
  }
}

// ---------------- winner map: numpy last-write-wins scatter == atomicMax on l
__global__ void k_win(const int* __restrict__ dp, int* __restrict__ win) {
  int i = blockIdx.x*256 + threadIdx.x;
  if (i >= Bn*Lq) return;
  int b = i / Lq, l = i % Lq;
  int p0 = dp[(size_t)(b*2+0)*Lq + l];
  int p1 = dp[(size_t)(b*2+1)*Lq + l];
  atomicMax(&win[(size_t)b*Lq*Lq + (size_t)p0*Lq + p1], l);
}

// ---------------- pack (win[i][j], win[j][i]) into one u32 map
__global__ __launch_bounds__(256) void k_pair(
    const int* __restrict__ win, unsigned int* __restrict__ wpair)
{
  __shared__ int tB[32][33];
  int b = blockIdx.z;
  int i0 = blockIdx.x*32, j0 = blockIdx.y*32;
  const int* wb = win + (size_t)b*Lq*Lq;
  int tx = threadIdx.x & 31, ty = threadIdx.x >> 5;
  #pragma unroll
  for (int rr = 0; rr < 4; ++rr) {
    int r = ty + rr*8;
    tB[r][tx] = wb[(size_t)(j0+r)*Lq + i0 + tx];
  }
  __syncthreads();
  #pragma unroll
  for (int rr = 0; rr < 4; ++rr) {
    int ti = ty + rr*8;
    int i = i0 + ti, j = j0 + tx;
    int l1 = wb[(size_t)i*Lq + j];
    int l2 = tB[tx][ti];
    wpair[(size_t)b*Lq*Lq + (size_t)i*Lq + j] =
        ((unsigned)(l1 + 1) << 16) | (unsigned)(l2 + 1);
  }
}

// ---------------- g (tanh gate) and rlog (per-head rel logit) per (b,l)
__global__ __launch_bounds__(256) void k_grlog(
    const float* __restrict__ values, const float* __restrict__ relations,
    const int* __restrict__ dp, const int* __restrict__ rel_mask,
    const float* __restrict__ Age, const float* __restrict__ Agr,
    const float* __restrict__ Vr,
    float* __restrict__ g, float* __restrict__ rlog)
{
  int blk = blockIdx.x;
  int b = blk / Lq, l = blk % Lq;
  int tid = threadIdx.x, lane = tid & 63, wave = tid >> 6;
  __shared__ float relrow[Dm], hvrow[Dm];
  __shared__ float part[Hn][4];
  int rm = rel_mask[(size_t)b*Lq + l];
  int idx = dp[(size_t)(b*2)*Lq + l];
  const float* vrow = values + ((size_t)b*Lq + idx)*Dm;
  const float* rrow = relations + ((size_t)b*Lq + l)*Dm;
  for (int d = tid; d < Dm; d += 256) {
    relrow[d] = rm ? 0.f : rrow[d];
    hvrow[d]  = (rm || l == 0) ? 0.f : vrow[d];
  }
  __syncthreads();
  for (int h = 0; h < Hn; ++h) {
    float p = 0.f;
    for (int d = tid; d < Dm; d += 256)
      p = fmaf(hvrow[d], Age[h*Dm + d], fmaf(relrow[d], Agr[h*Dm + d], p));
    #pragma unroll
    for (int o = 32; o > 0; o >>= 1) p += __shfl_xor(p, o);
    if (lane == 0) part[h][wave] = p;
  }
  __syncthreads();
  if (tid < Hn) {
    int h = tid;
    float t = part[h][0] + part[h][1] + part[h][2] + part[h][3];
    g[((size_t)b*Hn + h)*Lq + l] = tanhf(t);
  }
  if (tid >= 64 && tid < 64 + Hn) {
    int h = tid - 64;
    float s = 0.f;
    #pragma unroll 8
    for (int j = 0; j < DH; ++j) s = fmaf(relrow[h*DH + j], Vr[h*DH + j], s);
    rlog[((size_t)b*Hn + h)*Lq + l] = s;
  }
}

// ---------------- f32 tiled GEMM: C[M][768] = alpha * A[M][768] @ W[768][768]
__global__ __launch_bounds__(256) void k_gemm(
    const float* __restrict__ A, const float* __restrict__ W,
    float* __restrict__ C, int M, float alpha)
{
  const int N = Dm, K = Dm;
  __shared__ float As[32][64];   // [k][m]
  __shared__ float Bs[32][64];   // [k][n]
  int mb = M / 64;
  int bm = blockIdx.x % mb;
  int bn = blockIdx.x / mb;
  int m0 = bm*64, n0 = bn*64;
  int tid = threadIdx.x;
  int tx = tid & 15, ty = tid >> 4;
  float acc[4][4] = {};
  for (int k0 = 0; k0 < K; k0 += 32) {
    __syncthreads();
    #pragma unroll
    for (int u = 0; u < 2; ++u) {
      int idx = tid*2 + u;                 // 0..511
      int r = idx >> 3, cq = idx & 7;      // A: 64 rows x 8 float4
      float4 av = *(const float4*)&A[(size_t)(m0+r)*K + k0 + cq*4];
      As[cq*4+0][r] = av.x; As[cq*4+1][r] = av.y;
      As[cq*4+2][r] = av.z; As[cq*4+3][r] = av.w;
      int kr = idx >> 4, nq = idx & 15;    // B: 32 k x 16 float4
      *(float4*)&Bs[kr][nq*4] = *(const float4*)&W[(size_t)(k0+kr)*N + n0 + nq*4];
    }
    __syncthreads();
    #pragma unroll
    for (int kk = 0; kk < 32; ++kk) {
      float4 a  = *(const float4*)&As[kk][ty*4];
      float4 bv = *(const float4*)&Bs[kk][tx*4];
      float av4[4] = {a.x, a.y, a.z, a.w};
      float bv4[4] = {bv.x, bv.y, bv.z, bv.w};
      #pragma unroll
      for (int i = 0; i < 4; ++i)
        #pragma unroll
        for (int j = 0; j < 4; ++j)
          acc[i][j] = fmaf(av4[i], bv4[j], acc[i][j]);
    }
  }
  #pragma unroll
  for (int i = 0; i < 4; ++i) {
    float4 o;
    o.x = acc[i][0]*alpha; o.y = acc[i][1]*alpha;
    o.z = acc[i][2]*alpha; o.w = acc[i][3]*alpha;
    *(float4*)&C[(size_t)(m0+ty*4+i)*N + n0 + tx*4] = o;
  }
}

// ---------------- aw = batched q @ kT / 12, masked -> NEG   (M=N=384, K=768)
__global__ __launch_bounds__(256) void k_awgemm(
    const float* __restrict__ q, const float* __restrict__ kT,
    const int* __restrict__ mask, float* __restrict__ aw)
{
  const int N = Lq, K = Dm;
  __shared__ float As[32][64];
  __shared__ float Bs[32][64];
  int b = blockIdx.y;
  int bm = blockIdx.x % (Lq/64);
  int bn = blockIdx.x / (Lq/64);
  int m0 = bm*64, n0 = bn*64;
  const float* A = q  + (size_t)b*Lq*Dm;
  const float* W = kT + (size_t)b*Dm*Lq;
  int tid = threadIdx.x, tx = tid & 15, ty = tid >> 4;
  float acc[4][4] = {};
  for (int k0 = 0; k0 < K; k0 += 32) {
    __syncthreads();
    #pragma unroll
    for (int u = 0; u < 2; ++u) {
      int idx = tid*2 + u;
      int r = idx >> 3, cq = idx & 7;
      float4 av = *(const float4*)&A[(size_t)(m0+r)*K + k0 + cq*4];
      As[cq*4+0][r] = av.x; As[cq*4+1][r] = av.y;
      As[cq*4+2][r] = av.z; As[cq*4+3][r] = av.w;
      int kr = idx >> 4, nq = idx & 15;
      *(float4*)&Bs[kr][nq*4] = *(const float4*)&W[(size_t)(k0+kr)*N + n0 + nq*4];
    }
    __syncthreads();
    #pragma unroll
    for (int kk = 0; kk < 32; ++kk) {
      float4 a  = *(const float4*)&As[kk][ty*4];
      float4 bv = *(const float4*)&Bs[kk][tx*4];
      float av4[4] = {a.x, a.y, a.z, a.w};
      float bv4[4] = {bv.x, bv.y, bv.z, bv.w};
      #pragma unroll
      for (int i = 0; i < 4; ++i)
        #pragma unroll
        for (int j = 0; j < 4; ++j)
          acc[i][j] = fmaf(av4[i], bv4[j], acc[i][j]);
    }
  }
  const int* mb2 = mask + (size_t)b*Lq*Lq;
  float* awb = aw + (size_t)b*Lq*Lq;
  #pragma unroll
  for (int i = 0; i < 4; ++i) {
    int row = m0 + ty*4 + i;
    int4 mv = *(const int4*)&mb2[(size_t)row*Lq + n0 + tx*4];
    float4 o;
    o.x = mv.x ? NEGV : acc[i][0]*(1.f/12.f);
    o.y = mv.y ? NEGV : acc[i][1]*(1.f/12.f);
    o.z = mv.z ? NEGV : acc[i][2]*(1.f/12.f);
    o.w = mv.w ? NEGV : acc[i][3]*(1.f/12.f);
    *(float4*)&awb[(size_t)row*Lq + n0 + tx*4] = o;
  }
}

// ---------------- transpose (B,L,D) -> (B,D,L)
__global__ __launch_bounds__(256) void k_transpose(
    const float* __restrict__ in, float* __restrict__ out)
{
  __shared__ float t[32][33];
  int b = blockIdx.z;
  int l0 = blockIdx.x*32, d0 = blockIdx.y*32;
  int tx = threadIdx.x & 31, ty = threadIdx.x >> 5;   // 32 x 8
  #pragma unroll
  for (int r = 0; r < 4; ++r) {
    int ll = ty + r*8;
    t[ll][tx] = in[((size_t)b*Lq + l0 + ll)*Dm + d0 + tx];
  }
  __syncthreads();
  #pragma unroll
  for (int r = 0; r < 4; ++r) {
    int dl = ty + r*8;
    out[((size_t)b*Dm + d0 + dl)*Lq + l0 + tx] = t[tx][dl];
  }
}

// ---------------- fused per-(b,h,16-q-rows) attention
__global__ __launch_bounds__(256) void k_attn2(
    const float* __restrict__ q, const float* __restrict__ kT,
    const float* __restrict__ v, const unsigned int* __restrict__ wpair,
    const float* __restrict__ g, const float* __restrict__ rlog,
    const int* __restrict__ mask, float* __restrict__ ctxm)
{
  __shared__ float S[QT2][Lq];        // 24KB: logits, then combined weights
  __shared__ float qs[QT2][DH];       // 4KB
  __shared__ float rh_s[Lq];          // 1.5KB
  __shared__ float gh_s[Lq];          // 1.5KB

  int bid = blockIdx.x;
  int h  = bid % Hn;
  int qt = (bid / Hn) % (Lq/QT2);
  int b  = bid / (Hn * (Lq/QT2));
  int q0 = qt * QT2;
  int tid = threadIdx.x, lane = tid & 63, wave = tid >> 6;
  int w4 = wave*4;

  const float* kTh = kT + ((size_t)b*Dm + h*DH)*Lq;
  const int* maskb = mask + (size_t)b*Lq*Lq;
  const unsigned int* wpb = wpair + (size_t)b*Lq*Lq;
  const float* gh = g    + ((size_t)b*Hn + h)*Lq;
  const float* rh = rlog + ((size_t)b*Hn + h)*Lq;

  for (int e = tid; e < QT2*DH; e += 256) {
    int r = e >> 6, d = e & 63;
    qs[r][d] = q[((size_t)b*Lq + q0 + r)*Dm + h*DH + d];
  }
  for (int e = tid; e < Lq; e += 256) { rh_s[e] = rh[e]; gh_s[e] = gh[e]; }
  __syncthreads();

  // Phase 1: QK logits (each wave owns 4 q-rows, each lane a k-column per chunk)
  for (int s = 0; s < 6; ++s) {
    int kj = s*64 + lane;
    const float* kp = kTh + kj;
    float a0 = 0.f, a1 = 0.f, a2 = 0.f, a3 = 0.f;
    #pragma unroll 8
    for (int d = 0; d < DH; ++d) {
      float kv = kp[(size_t)d*Lq];
      a0 = fmaf(qs[w4+0][d], kv, a0);
      a1 = fmaf(qs[w4+1][d], kv, a1);
      a2 = fmaf(qs[w4+2][d], kv, a2);
      a3 = fmaf(qs[w4+3][d], kv, a3);
    }
    float av[4] = {a0, a1, a2, a3};
    #pragma unroll
    for (int r = 0; r < 4; ++r) {
      int m = maskb[(size_t)(q0 + w4 + r)*Lq + kj];
      S[w4+r][kj] = m ? NEGV : av[r];
    }
  }
  __syncthreads();

  // Phase 2: dual softmax + gate combine, one row at a time per wave
  for (int r = 0; r < 4; ++r) {
    int row = w4 + r, i = q0 + row;
    float sv[6], rv[6];
    unsigned int wp[6];
    float smax = -3.0e38f, rmax = -3.0e38f;
    #pragma unroll
    for (int u = 0; u < 6; ++u) {
      int kj = u*64 + lane;
      sv[u] = S[row][kj];
      wp[u] = wpb[(size_t)i*Lq + kj];
      float rel;
      if (sv[u] <= -5e17f) {               // masked sentinel
        rel = NEGV;
      } else {
        int l1 = (int)(wp[u] >> 16) - 1;
        int l2 = (int)(wp[u] & 0xFFFFu) - 1;
        rel = 0.f;
        if (l1 >= 0) rel += rh_s[l1];
        if (l2 >= 0) rel += rh_s[l2];
      }
      rv[u] = rel;
      smax = fmaxf(smax, sv[u]);
      rmax = fmaxf(rmax, rv[u]);
    }
    #pragma unroll
    for (int o = 32; o > 0; o >>= 1) {
      smax = fmaxf(smax, __shfl_xor(smax, o));
      rmax = fmaxf(rmax, __shfl_xor(rmax, o));
    }
    float ssum = 0.f, rsum = 0.f;
    #pragma unroll
    for (int u = 0; u < 6; ++u) {
      sv[u] = __expf(sv[u] - smax); ssum += sv[u];
      rv[u] = __expf(rv[u] - rmax); rsum += rv[u];
    }
    #pragma unroll
    for (int o = 32; o > 0; o >>= 1) {
      ssum += __shfl_xor(ssum, o);
      rsum += __shfl_xor(rsum, o);
    }
    float si = 1.f/ssum, ri = 1.f/rsum;
    #pragma unroll
    for (int u = 0; u < 6; ++u) {
      int kj = u*64 + lane;
      int l1 = (int)(wp[u] >> 16) - 1;
      int l2 = (int)(wp[u] & 0xFFFFu) - 1;
      float gv = 0.f;
      if (l1 >= 0) gv += gh_s[l1];
      if (l2 >= 0) gv += gh_s[l2];
      S[row][kj] = (1.f - gv)*(sv[u]*si) + gv*(rv[u]*ri);
    }
  }
  __syncthreads();

  // Phase 3: PV (lane = output dim, wave owns 4 q-rows)
  {
    int d = lane;
    const float* vb = v + (size_t)b*Lq*Dm + h*DH + d;
    float a0 = 0.f, a1 = 0.f, a2 = 0.f, a3 = 0.f;
    #pragma unroll 4
    for (int kj = 0; kj < Lq; ++kj) {
      float vv = vb[(size_t)kj*Dm];
      a0 = fmaf(S[w4+0][kj], vv, a0);
      a1 = fmaf(S[w4+1][kj], vv, a1);
      a2 = fmaf(S[w4+2][kj], vv, a2);
      a3 = fmaf(S[w4+3][kj], vv, a3);
    }
    float av[4] = {a0, a1, a2, a3};
    #pragma unroll
    for (int r = 0; r < 4; ++r)
      ctxm[((size_t)b*Lq + q0 + w4 + r)*Dm + h*DH + d] = av[r];
  }
}

extern "C" void kernel_launch(void* const* d_in, const int* in_sizes, int n_in,
                              void* d_out, int out_size, void* d_ws, size_t ws_size,
                              hipStream_t stream) {
  const float* queries   = (const float*)d_in[0];
  const float* keys      = (const float*)d_in[1];
  const float* values    = (const float*)d_in[2];
  const float* relations = (const float*)d_in[3];
  const int*   dp_map    = (const int*)d_in[4];
  const int*   mask      = (const int*)d_in[5];
  const int*   rel_mask  = (const int*)d_in[6];
  const float* Wq  = (const float*)d_in[7];
  const float* Wk  = (const float*)d_in[8];
  const float* Wv  = (const float*)d_in[9];
  const float* Wo  = (const float*)d_in[10];
  const float* Wge = (const float*)d_in[11];
  const float* Wgr = (const float*)d_in[12];
  const float* Vr  = (const float*)d_in[13];
  const float* Vg  = (const float*)d_in[14];

  float* ws = (float*)d_ws;
  const size_t SZ = (size_t)Bn*Lq*Dm;          // 4718592
  float* q    = ws;
  float* k    = ws + SZ;                       // dead after transpose; reused as wpair
  float* kT   = ws + 2*SZ;
  float* v    = ws + 3*SZ;
  float* ctxm = ws + 4*SZ;
  int*   win  = (int*)(ws + 5*SZ);
  float* g    = ws + 5*SZ + (size_t)Bn*Lq*Lq;
  float* rlog = g + (size_t)Bn*Hn*Lq;
  float* Age  = rlog + (size_t)Bn*Hn*Lq;
  float* Agr  = Age + (size_t)Hn*Dm;
  unsigned int* wpair = (unsigned int*)k;      // alias: k unused after k_transpose

  float* outp = (float*)d_out;                 // (B,L,D)
  float* awp  = outp + SZ;                     // (B,L,L)

  const int M = Bn*Lq;                         // 6144

  hipMemsetAsync(win, 0xFF, (size_t)Bn*Lq*Lq*sizeof(int), stream);
  k_prep_age<<<2*Hn, 256, 0, stream>>>(Wge, Wgr, Vg, Age, Agr);
  k_win<<<(Bn*Lq + 255)/256, 256, 0, stream>>>(dp_map, win);
  k_grlog<<<Bn*Lq, 256, 0, stream>>>(values, relations, dp_map, rel_mask,
                                     Age, Agr, Vr, g, rlog);
  k_gemm<<<(M/64)*(Dm/64), 256, 0, stream>>>(queries, Wq, q, M, 0.125f);
  k_gemm<<<(M/64)*(Dm/64), 256, 0, stream>>>(keys,    Wk, k, M, 1.f);
  k_gemm<<<(M/64)*(Dm/64), 256, 0, stream>>>(values,  Wv, v, M, 1.f);
  k_transpose<<<dim3(Lq/32, Dm/32, Bn), 256, 0, stream>>>(k, kT);
  k_pair<<<dim3(Lq/32, Lq/32, Bn), 256, 0, stream>>>(win, wpair);
  k_awgemm<<<dim3((Lq/64)*(Lq/64), Bn), 256, 0, stream>>>(q, kT, mask, awp);
  k_attn2<<<Bn*(Lq/QT2)*Hn, 256, 0, stream>>>(q, kT, v, wpair, g, rlog,
                                              mask, ctxm);
  k_gemm<<<(M/64)*(Dm/64), 256, 0, stream>>>(ctxm, Wo, outp, M, 1.f);
}

// Round 3
// 461.372 us; speedup vs baseline: 3.9829x; 1.8134x over previous
//
#include <hip/hip_runtime.h>
#include <math.h>

#define Bn 16
#define Lq 384
#define Hn 12
#define Dm 768
#define DH 64
#define QT2 16
#define NEGV (-1e18f)

typedef __attribute__((ext_vector_type(4))) float f32x4;
typedef __attribute__((ext_vector_type(8))) __bf16 bf16x8;
typedef unsigned short ushort_t;
typedef unsigned int uint_t;

__device__ __forceinline__ ushort_t f2b(float f) {
  unsigned int u = __float_as_uint(f);
  unsigned int r = (u + 0x7FFFu + ((u >> 16) & 1u)) >> 16;
  return (ushort_t)r;
}
__device__ __forceinline__ float b2f(ushort_t u) {
  return __uint_as_float(((unsigned int)u) << 16);
}

// ---------------- Age/Agr precompute
__global__ __launch_bounds__(256) void k_prep_age(
    const float* __restrict__ Wge, const float* __restrict__ Wgr,
    const float* __restrict__ Vg, float* __restrict__ Age, float* __restrict__ Agr)
{
  int which = blockIdx.x / Hn;
  int h = blockIdx.x % Hn;
  const float* Wsrc = which ? Wgr : Wge;
  float* dst = which ? Agr : Age;
  __shared__ float vg[DH];
  if (threadIdx.x < DH) vg[threadIdx.x] = Vg[h*DH + threadIdx.x];
  __syncthreads();
  for (int d = threadIdx.x; d < Dm; d += 256) {
    const float* wrow = Wsrc + (size_t)d*Dm + h*DH;
    float s = 0.f;
    #pragma unroll 8
    for (int j = 0; j < DH; ++j) s = fmaf(wrow[j], vg[j], s);
    dst[h*Dm + d] = s;
  }
}

// ---------------- winner map
__global__ void k_win(const int* __restrict__ dp, int* __restrict__ win) {
  int i = blockIdx.x*256 + threadIdx.x;
  if (i >= Bn*Lq) return;
  int b = i / Lq, l = i % Lq;
  int p0 = dp[(size_t)(b*2+0)*Lq + l];
  int p1 = dp[(size_t)(b*2+1)*Lq + l];
  atomicMax(&win[(size_t)b*Lq*Lq + (size_t)p0*Lq + p1], l);
}

// ---------------- pack (win[i][j], win[j][i]) into one u32 map
__global__ __launch_bounds__(256) void k_pair(
    const int* __restrict__ win, uint_t* __restrict__ wpair)
{
  __shared__ int tB[32][33];
  int b = blockIdx.z;
  int i0 = blockIdx.x*32, j0 = blockIdx.y*32;
  const int* wb = win + (size_t)b*Lq*Lq;
  int tx = threadIdx.x & 31, ty = threadIdx.x >> 5;
  #pragma unroll
  for (int rr = 0; rr < 4; ++rr) {
    int r = ty + rr*8;
    tB[r][tx] = wb[(size_t)(j0+r)*Lq + i0 + tx];
  }
  __syncthreads();
  #pragma unroll
  for (int rr = 0; rr < 4; ++rr) {
    int ti = ty + rr*8;
    int i = i0 + ti, j = j0 + tx;
    int l1 = wb[(size_t)i*Lq + j];
    int l2 = tB[tx][ti];
    wpair[(size_t)b*Lq*Lq + (size_t)i*Lq + j] =
        ((unsigned)(l1 + 1) << 16) | (unsigned)(l2 + 1);
  }
}

// ---------------- g (tanh gate) and rlog per (b,l)
__global__ __launch_bounds__(256) void k_grlog(
    const float* __restrict__ values, const float* __restrict__ relations,
    const int* __restrict__ dp, const int* __restrict__ rel_mask,
    const float* __restrict__ Age, const float* __restrict__ Agr,
    const float* __restrict__ Vr,
    float* __restrict__ g, float* __restrict__ rlog)
{
  int blk = blockIdx.x;
  int b = blk / Lq, l = blk % Lq;
  int tid = threadIdx.x, lane = tid & 63, wave = tid >> 6;
  __shared__ float relrow[Dm], hvrow[Dm];
  __shared__ float part[Hn][4];
  int rm = rel_mask[(size_t)b*Lq + l];
  int idx = dp[(size_t)(b*2)*Lq + l];
  const float* vrow = values + ((size_t)b*Lq + idx)*Dm;
  const float* rrow = relations + ((size_t)b*Lq + l)*Dm;
  for (int d = tid; d < Dm; d += 256) {
    relrow[d] = rm ? 0.f : rrow[d];
    hvrow[d]  = (rm || l == 0) ? 0.f : vrow[d];
  }
  __syncthreads();
  for (int h = 0; h < Hn; ++h) {
    float p = 0.f;
    for (int d = tid; d < Dm; d += 256)
      p = fmaf(hvrow[d], Age[h*Dm + d], fmaf(relrow[d], Agr[h*Dm + d], p));
    #pragma unroll
    for (int o = 32; o > 0; o >>= 1) p += __shfl_xor(p, o);
    if (lane == 0) part[h][wave] = p;
  }
  __syncthreads();
  if (tid < Hn) {
    int h = tid;
    float t = part[h][0] + part[h][1] + part[h][2] + part[h][3];
    g[((size_t)b*Hn + h)*Lq + l] = tanhf(t);
  }
  if (tid >= 64 && tid < 64 + Hn) {
    int h = tid - 64;
    float s = 0.f;
    #pragma unroll 8
    for (int j = 0; j < DH; ++j) s = fmaf(relrow[h*DH + j], Vr[h*DH + j], s);
    rlog[((size_t)b*Hn + h)*Lq + l] = s;
  }
}

// ---------------- f32 -> bf16 convert (4 floats/thread)
__global__ __launch_bounds__(256) void k_f2b(
    const float* __restrict__ in, ushort_t* __restrict__ out)
{
  int i = blockIdx.x*256 + threadIdx.x;
  float4 f = ((const float4*)in)[i];
  ushort4 u;
  u.x = f2b(f.x); u.y = f2b(f.y); u.z = f2b(f.z); u.w = f2b(f.w);
  ((ushort4*)out)[i] = u;
}

// ---------------- W[768][768] f32 -> WT[768][768] bf16 (transposed)
__global__ __launch_bounds__(256) void k_wT(
    const float* __restrict__ W, ushort_t* __restrict__ WT)
{
  __shared__ float t[32][33];
  int k0 = blockIdx.x*32, n0 = blockIdx.y*32;
  int tx = threadIdx.x & 31, ty = threadIdx.x >> 5;
  #pragma unroll
  for (int r = 0; r < 4; ++r)
    t[ty + r*8][tx] = W[(size_t)(k0 + ty + r*8)*Dm + n0 + tx];
  __syncthreads();
  #pragma unroll
  for (int r = 0; r < 4; ++r)
    WT[(size_t)(n0 + ty + r*8)*Dm + k0 + tx] = f2b(t[tx][ty + r*8]);
}

// ---------------- bf16 MFMA GEMM: C = alpha * A[6144][768] @ BT[n][768]^T
// MODE 0: f32 out normal.  MODE 1: bf16 out normal (alpha).
// MODE 2: f32 out TRANSPOSED per-batch (kT[b][n][l]) + bf16 out normal.
// MODE 3: batched aw: per-batch M=N=384, mask epilogue, *alpha, NEGV fill.
template<int MODE>
__global__ __launch_bounds__(256) void k_mm(
    const ushort_t* __restrict__ A, const ushort_t* __restrict__ BT,
    float* __restrict__ Cf, ushort_t* __restrict__ Cb,
    const int* __restrict__ mask, float alpha)
{
  const int K = Dm;
  __shared__ ushort_t As[128*64];
  __shared__ ushort_t Bs[128*64];

  int bm = blockIdx.x;                  // 0..47
  int bn = blockIdx.y;                  // 0..5 (or 0..2 MODE 3)
  int m_blk = bm*128;
  int brow0 = (MODE == 3) ? ((bm/3)*Lq + bn*128) : bn*128;

  int t = threadIdx.x;
  int wave = t >> 6, lane = t & 63;
  int wr = wave >> 1, wc = wave & 1;
  int lrow = lane & 15, lkg = lane >> 4;     // 0..3

  f32x4 acc[4][4];
  #pragma unroll
  for (int i = 0; i < 4; ++i)
    #pragma unroll
    for (int j = 0; j < 4; ++j) acc[i][j] = (f32x4)(0.f);

  int sr = t >> 3, sc8 = t & 7;              // staging: row, 16B-chunk
  for (int k0 = 0; k0 < K; k0 += 64) {
    __syncthreads();
    #pragma unroll
    for (int i = 0; i < 4; ++i) {
      int row = sr + i*32;
      uint4 va = *(const uint4*)(A  + (size_t)(m_blk + row)*K + k0 + sc8*8);
      uint4 vb = *(const uint4*)(BT + (size_t)(brow0 + row)*K + k0 + sc8*8);
      int slot = sc8 ^ (row & 7);
      *(uint4*)&As[row*64 + slot*8] = va;
      *(uint4*)&Bs[row*64 + slot*8] = vb;
    }
    __syncthreads();
    #pragma unroll
    for (int kk = 0; kk < 2; ++kk) {
      bf16x8 aF[4], bF[4];
      int chunk = kk*4 + lkg;
      #pragma unroll
      for (int mi = 0; mi < 4; ++mi) {
        int arow = wr*64 + mi*16 + lrow;
        aF[mi] = *(const bf16x8*)&As[arow*64 + ((chunk ^ (arow & 7)) << 3)];
        int brow = wc*64 + mi*16 + lrow;
        bF[mi] = *(const bf16x8*)&Bs[brow*64 + ((chunk ^ (brow & 7)) << 3)];
      }
      #pragma unroll
      for (int mi = 0; mi < 4; ++mi)
        #pragma unroll
        for (int ni = 0; ni < 4; ++ni)
          acc[mi][ni] = __builtin_amdgcn_mfma_f32_16x16x32_bf16(
              aF[mi], bF[ni], acc[mi][ni], 0, 0, 0);
    }
  }

  // epilogue: C/D frag mapping col=lane&15, row=4*(lane>>4)+reg  [m89/m91]
  #pragma unroll
  for (int mi = 0; mi < 4; ++mi) {
    #pragma unroll
    for (int ni = 0; ni < 4; ++ni) {
      f32x4 a = acc[mi][ni];
      int rit = wr*64 + mi*16 + 4*lkg;        // row in tile (base of 4)
      int cit = wc*64 + ni*16 + lrow;         // col in tile
      if (MODE == 0) {
        int grow = m_blk + rit, gcol = bn*128 + cit;
        #pragma unroll
        for (int r = 0; r < 4; ++r)
          Cf[(size_t)(grow + r)*Dm + gcol] = a[r]*alpha;
      } else if (MODE == 1) {
        int grow = m_blk + rit, gcol = bn*128 + cit;
        #pragma unroll
        for (int r = 0; r < 4; ++r)
          Cb[(size_t)(grow + r)*Dm + gcol] = f2b(a[r]*alpha);
      } else if (MODE == 2) {
        int grow = m_blk + rit, gcol = bn*128 + cit;
        #pragma unroll
        for (int r = 0; r < 4; ++r)
          Cb[(size_t)(grow + r)*Dm + gcol] = f2b(a[r]);
        int b = bm/3;
        int rl = (bm%3)*128 + rit;
        float4 o; o.x = a[0]; o.y = a[1]; o.z = a[2]; o.w = a[3];
        *(float4*)&Cf[((size_t)b*Dm + gcol)*Lq + rl] = o;
      } else {  // MODE 3
        int b = bm/3;
        int rl = (bm%3)*128 + rit;
        int cl = bn*128 + cit;
        const int* mb2 = mask + (size_t)b*Lq*Lq;
        float* awb = Cf + (size_t)b*Lq*Lq;
        #pragma unroll
        for (int r = 0; r < 4; ++r) {
          int m = mb2[(size_t)(rl + r)*Lq + cl];
          awb[(size_t)(rl + r)*Lq + cl] = m ? NEGV : a[r]*alpha;
        }
      }
    }
  }
}

// ---------------- fused per-(b,h,16-q-rows) attention (bf16 q in, bf16 ctx out)
__global__ __launch_bounds__(256) void k_attn2(
    const ushort_t* __restrict__ qbf, const float* __restrict__ kT,
    const float* __restrict__ v, const uint_t* __restrict__ wpair,
    const float* __restrict__ g, const float* __restrict__ rlog,
    const int* __restrict__ mask, ushort_t* __restrict__ ctxbf)
{
  __shared__ float S[QT2][Lq];
  __shared__ float qs[QT2][DH];
  __shared__ float rh_s[Lq];
  __shared__ float gh_s[Lq];

  int bid = blockIdx.x;
  int h  = bid % Hn;
  int qt = (bid / Hn) % (Lq/QT2);
  int b  = bid / (Hn * (Lq/QT2));
  int q0 = qt * QT2;
  int tid = threadIdx.x, lane = tid & 63, wave = tid >> 6;
  int w4 = wave*4;

  const float* kTh = kT + ((size_t)b*Dm + h*DH)*Lq;
  const int* maskb = mask + (size_t)b*Lq*Lq;
  const uint_t* wpb = wpair + (size_t)b*Lq*Lq;
  const float* gh = g    + ((size_t)b*Hn + h)*Lq;
  const float* rh = rlog + ((size_t)b*Hn + h)*Lq;

  for (int e = tid; e < QT2*DH; e += 256) {
    int r = e >> 6, d = e & 63;
    qs[r][d] = b2f(qbf[((size_t)b*Lq + q0 + r)*Dm + h*DH + d]);
  }
  for (int e = tid; e < Lq; e += 256) { rh_s[e] = rh[e]; gh_s[e] = gh[e]; }
  __syncthreads();

  // Phase 1: QK logits
  for (int s = 0; s < 6; ++s) {
    int kj = s*64 + lane;
    const float* kp = kTh + kj;
    float a0 = 0.f, a1 = 0.f, a2 = 0.f, a3 = 0.f;
    #pragma unroll 8
    for (int d = 0; d < DH; ++d) {
      float kv = kp[(size_t)d*Lq];
      a0 = fmaf(qs[w4+0][d], kv, a0);
      a1 = fmaf(qs[w4+1][d], kv, a1);
      a2 = fmaf(qs[w4+2][d], kv, a2);
      a3 = fmaf(qs[w4+3][d], kv, a3);
    }
    float av[4] = {a0, a1, a2, a3};
    #pragma unroll
    for (int r = 0; r < 4; ++r) {
      int m = maskb[(size_t)(q0 + w4 + r)*Lq + kj];
      S[w4+r][kj] = m ? NEGV : av[r];
    }
  }
  __syncthreads();

  // Phase 2: dual softmax + gate combine
  for (int r = 0; r < 4; ++r) {
    int row = w4 + r, i = q0 + row;
    float sv[6], rv[6];
    uint_t wp[6];
    float smax = -3.0e38f, rmax = -3.0e38f;
    #pragma unroll
    for (int u = 0; u < 6; ++u) {
      int kj = u*64 + lane;
      sv[u] = S[row][kj];
      wp[u] = wpb[(size_t)i*Lq + kj];
      float rel;
      if (sv[u] <= -5e17f) {
        rel = NEGV;
      } else {
        int l1 = (int)(wp[u] >> 16) - 1;
        int l2 = (int)(wp[u] & 0xFFFFu) - 1;
        rel = 0.f;
        if (l1 >= 0) rel += rh_s[l1];
        if (l2 >= 0) rel += rh_s[l2];
      }
      rv[u] = rel;
      smax = fmaxf(smax, sv[u]);
      rmax = fmaxf(rmax, rv[u]);
    }
    #pragma unroll
    for (int o = 32; o > 0; o >>= 1) {
      smax = fmaxf(smax, __shfl_xor(smax, o));
      rmax = fmaxf(rmax, __shfl_xor(rmax, o));
    }
    float ssum = 0.f, rsum = 0.f;
    #pragma unroll
    for (int u = 0; u < 6; ++u) {
      sv[u] = __expf(sv[u] - smax); ssum += sv[u];
      rv[u] = __expf(rv[u] - rmax); rsum += rv[u];
    }
    #pragma unroll
    for (int o = 32; o > 0; o >>= 1) {
      ssum += __shfl_xor(ssum, o);
      rsum += __shfl_xor(rsum, o);
    }
    float si = 1.f/ssum, ri = 1.f/rsum;
    #pragma unroll
    for (int u = 0; u < 6; ++u) {
      int kj = u*64 + lane;
      int l1 = (int)(wp[u] >> 16) - 1;
      int l2 = (int)(wp[u] & 0xFFFFu) - 1;
      float gv = 0.f;
      if (l1 >= 0) gv += gh_s[l1];
      if (l2 >= 0) gv += gh_s[l2];
      S[row][kj] = (1.f - gv)*(sv[u]*si) + gv*(rv[u]*ri);
    }
  }
  __syncthreads();

  // Phase 3: PV
  {
    int d = lane;
    const float* vb = v + (size_t)b*Lq*Dm + h*DH + d;
    float a0 = 0.f, a1 = 0.f, a2 = 0.f, a3 = 0.f;
    #pragma unroll 4
    for (int kj = 0; kj < Lq; ++kj) {
      float vv = vb[(size_t)kj*Dm];
      a0 = fmaf(S[w4+0][kj], vv, a0);
      a1 = fmaf(S[w4+1][kj], vv, a1);
      a2 = fmaf(S[w4+2][kj], vv, a2);
      a3 = fmaf(S[w4+3][kj], vv, a3);
    }
    float av[4] = {a0, a1, a2, a3};
    #pragma unroll
    for (int r = 0; r < 4; ++r)
      ctxbf[((size_t)b*Lq + q0 + w4 + r)*Dm + h*DH + d] = f2b(av[r]);
  }
}

extern "C" void kernel_launch(void* const* d_in, const int* in_sizes, int n_in,
                              void* d_out, int out_size, void* d_ws, size_t ws_size,
                              hipStream_t stream) {
  const float* queries   = (const float*)d_in[0];
  const float* keys      = (const float*)d_in[1];
  const float* values    = (const float*)d_in[2];
  const float* relations = (const float*)d_in[3];
  const int*   dp_map    = (const int*)d_in[4];
  const int*   mask      = (const int*)d_in[5];
  const int*   rel_mask  = (const int*)d_in[6];
  const float* Wq  = (const float*)d_in[7];
  const float* Wk  = (const float*)d_in[8];
  const float* Wv  = (const float*)d_in[9];
  const float* Wo  = (const float*)d_in[10];
  const float* Wge = (const float*)d_in[11];
  const float* Wgr = (const float*)d_in[12];
  const float* Vr  = (const float*)d_in[13];
  const float* Vg  = (const float*)d_in[14];

  float* ws = (float*)d_ws;
  const size_t SZ   = (size_t)Bn*Lq*Dm;      // 4718592
  const size_t WINS = (size_t)Bn*Lq*Lq;      // 2359296
  const size_t GSZ  = (size_t)Bn*Hn*Lq;      // 73728

  float* kT   = ws;
  float* v    = ws + SZ;
  int*   win  = (int*)(ws + 2*SZ);
  float* g    = ws + 2*SZ + WINS;
  float* rlog = g + GSZ;
  float* Age  = rlog + GSZ;
  float* Agr  = Age + (size_t)Hn*Dm;
  ushort_t* Ibf = (ushort_t*)(Agr + (size_t)Hn*Dm);
  uint_t* wpair = (uint_t*)Ibf;              // alias: Ibf dead after v-GEMM
  ushort_t* qbf = Ibf + SZ;
  ushort_t* kbf = qbf + SZ;
  ushort_t* ctxbf = kbf;                     // alias: kbf dead after awgemm
  ushort_t* WqT = kbf + SZ;
  ushort_t* WkT = WqT + (size_t)Dm*Dm;
  ushort_t* WvT = WkT + (size_t)Dm*Dm;
  ushort_t* WoT = WvT + (size_t)Dm*Dm;

  float* outp = (float*)d_out;               // (B,L,D)
  float* awp  = outp + SZ;                   // (B,L,L)

  hipMemsetAsync(win, 0xFF, WINS*sizeof(int), stream);
  k_prep_age<<<2*Hn, 256, 0, stream>>>(Wge, Wgr, Vg, Age, Agr);
  k_win<<<(Bn*Lq + 255)/256, 256, 0, stream>>>(dp_map, win);
  k_grlog<<<Bn*Lq, 256, 0, stream>>>(values, relations, dp_map, rel_mask,
                                     Age, Agr, Vr, g, rlog);
  k_wT<<<dim3(Dm/32, Dm/32), 256, 0, stream>>>(Wq, WqT);
  k_wT<<<dim3(Dm/32, Dm/32), 256, 0, stream>>>(Wk, WkT);
  k_wT<<<dim3(Dm/32, Dm/32), 256, 0, stream>>>(Wv, WvT);
  k_wT<<<dim3(Dm/32, Dm/32), 256, 0, stream>>>(Wo, WoT);

  k_f2b<<<SZ/4/256, 256, 0, stream>>>(queries, Ibf);
  k_mm<1><<<dim3(48, 6), 256, 0, stream>>>(Ibf, WqT, nullptr, qbf, nullptr, 0.125f);
  k_f2b<<<SZ/4/256, 256, 0, stream>>>(keys, Ibf);
  k_mm<2><<<dim3(48, 6), 256, 0, stream>>>(Ibf, WkT, kT, kbf, nullptr, 1.f);
  k_f2b<<<SZ/4/256, 256, 0, stream>>>(values, Ibf);
  k_mm<0><<<dim3(48, 6), 256, 0, stream>>>(Ibf, WvT, v, nullptr, nullptr, 1.f);

  k_pair<<<dim3(Lq/32, Lq/32, Bn), 256, 0, stream>>>(win, wpair);
  k_mm<3><<<dim3(48, 3), 256, 0, stream>>>(qbf, kbf, awp, nullptr, mask, 1.f/12.f);
  k_attn2<<<Bn*(Lq/QT2)*Hn, 256, 0, stream>>>(qbf, kT, v, wpair, g, rlog,
                                              mask, ctxbf);
  k_mm<0><<<dim3(48, 6), 256, 0, stream>>>(ctxbf, WoT, outp, nullptr, nullptr, 1.f);
}

// Round 4
// 328.169 us; speedup vs baseline: 5.5996x; 1.4059x over previous
//
#include <hip/hip_runtime.h>
#include <math.h>

#define Bn 16
#define Lq 384
#define Hn 12
#define Dm 768
#define DH 64
#define QT2 16
#define NEGV (-1e18f)

typedef __attribute__((ext_vector_type(4))) float f32x4;
typedef __attribute__((ext_vector_type(8))) __bf16 bf16x8;
typedef unsigned short ushort_t;
typedef unsigned int uint_t;

__device__ __forceinline__ ushort_t f2b(float f) {
  unsigned int u = __float_as_uint(f);
  unsigned int r = (u + 0x7FFFu + ((u >> 16) & 1u)) >> 16;
  return (ushort_t)r;
}
__device__ __forceinline__ float b2f(ushort_t u) {
  return __uint_as_float(((unsigned int)u) << 16);
}

// ---------------- Age/Agr precompute
__global__ __launch_bounds__(256) void k_prep_age(
    const float* __restrict__ Wge, const float* __restrict__ Wgr,
    const float* __restrict__ Vg, float* __restrict__ Age, float* __restrict__ Agr)
{
  int which = blockIdx.x / Hn;
  int h = blockIdx.x % Hn;
  const float* Wsrc = which ? Wgr : Wge;
  float* dst = which ? Agr : Age;
  __shared__ float vg[DH];
  if (threadIdx.x < DH) vg[threadIdx.x] = Vg[h*DH + threadIdx.x];
  __syncthreads();
  for (int d = threadIdx.x; d < Dm; d += 256) {
    const float* wrow = Wsrc + (size_t)d*Dm + h*DH;
    float s = 0.f;
    #pragma unroll 8
    for (int j = 0; j < DH; ++j) s = fmaf(wrow[j], vg[j], s);
    dst[h*Dm + d] = s;
  }
}

// ---------------- winner map
__global__ void k_win(const int* __restrict__ dp, int* __restrict__ win) {
  int i = blockIdx.x*256 + threadIdx.x;
  if (i >= Bn*Lq) return;
  int b = i / Lq, l = i % Lq;
  int p0 = dp[(size_t)(b*2+0)*Lq + l];
  int p1 = dp[(size_t)(b*2+1)*Lq + l];
  atomicMax(&win[(size_t)b*Lq*Lq + (size_t)p0*Lq + p1], l);
}

// ---------------- pack (win[i][j], win[j][i]) into one u32 map
__global__ __launch_bounds__(256) void k_pair(
    const int* __restrict__ win, uint_t* __restrict__ wpair)
{
  __shared__ int tB[32][33];
  int b = blockIdx.z;
  int i0 = blockIdx.x*32, j0 = blockIdx.y*32;
  const int* wb = win + (size_t)b*Lq*Lq;
  int tx = threadIdx.x & 31, ty = threadIdx.x >> 5;
  #pragma unroll
  for (int rr = 0; rr < 4; ++rr) {
    int r = ty + rr*8;
    tB[r][tx] = wb[(size_t)(j0+r)*Lq + i0 + tx];
  }
  __syncthreads();
  #pragma unroll
  for (int rr = 0; rr < 4; ++rr) {
    int ti = ty + rr*8;
    int i = i0 + ti, j = j0 + tx;
    int l1 = wb[(size_t)i*Lq + j];
    int l2 = tB[tx][ti];
    wpair[(size_t)b*Lq*Lq + (size_t)i*Lq + j] =
        ((unsigned)(l1 + 1) << 16) | (unsigned)(l2 + 1);
  }
}

// ---------------- g (tanh gate) and rlog per (b,l)
__global__ __launch_bounds__(256) void k_grlog(
    const float* __restrict__ values, const float* __restrict__ relations,
    const int* __restrict__ dp, const int* __restrict__ rel_mask,
    const float* __restrict__ Age, const float* __restrict__ Agr,
    const float* __restrict__ Vr,
    float* __restrict__ g, float* __restrict__ rlog)
{
  int blk = blockIdx.x;
  int b = blk / Lq, l = blk % Lq;
  int tid = threadIdx.x, lane = tid & 63, wave = tid >> 6;
  __shared__ float relrow[Dm], hvrow[Dm];
  __shared__ float part[Hn][4];
  int rm = rel_mask[(size_t)b*Lq + l];
  int idx = dp[(size_t)(b*2)*Lq + l];
  const float* vrow = values + ((size_t)b*Lq + idx)*Dm;
  const float* rrow = relations + ((size_t)b*Lq + l)*Dm;
  for (int d = tid; d < Dm; d += 256) {
    relrow[d] = rm ? 0.f : rrow[d];
    hvrow[d]  = (rm || l == 0) ? 0.f : vrow[d];
  }
  __syncthreads();
  for (int h = 0; h < Hn; ++h) {
    float p = 0.f;
    for (int d = tid; d < Dm; d += 256)
      p = fmaf(hvrow[d], Age[h*Dm + d], fmaf(relrow[d], Agr[h*Dm + d], p));
    #pragma unroll
    for (int o = 32; o > 0; o >>= 1) p += __shfl_xor(p, o);
    if (lane == 0) part[h][wave] = p;
  }
  __syncthreads();
  if (tid < Hn) {
    int h = tid;
    float t = part[h][0] + part[h][1] + part[h][2] + part[h][3];
    g[((size_t)b*Hn + h)*Lq + l] = tanhf(t);
  }
  if (tid >= 64 && tid < 64 + Hn) {
    int h = tid - 64;
    float s = 0.f;
    #pragma unroll 8
    for (int j = 0; j < DH; ++j) s = fmaf(relrow[h*DH + j], Vr[h*DH + j], s);
    rlog[((size_t)b*Hn + h)*Lq + l] = s;
  }
}

// ---------------- f32 -> bf16 convert (4 floats/thread)
__global__ __launch_bounds__(256) void k_f2b(
    const float* __restrict__ in, ushort_t* __restrict__ out)
{
  int i = blockIdx.x*256 + threadIdx.x;
  float4 f = ((const float4*)in)[i];
  ushort4 u;
  u.x = f2b(f.x); u.y = f2b(f.y); u.z = f2b(f.z); u.w = f2b(f.w);
  ((ushort4*)out)[i] = u;
}

// ---------------- W[768][768] f32 -> WT[768][768] bf16 (transposed)
__global__ __launch_bounds__(256) void k_wT(
    const float* __restrict__ W, ushort_t* __restrict__ WT)
{
  __shared__ float t[32][33];
  int k0 = blockIdx.x*32, n0 = blockIdx.y*32;
  int tx = threadIdx.x & 31, ty = threadIdx.x >> 5;
  #pragma unroll
  for (int r = 0; r < 4; ++r)
    t[ty + r*8][tx] = W[(size_t)(k0 + ty + r*8)*Dm + n0 + tx];
  __syncthreads();
  #pragma unroll
  for (int r = 0; r < 4; ++r)
    WT[(size_t)(n0 + ty + r*8)*Dm + k0 + tx] = f2b(t[tx][ty + r*8]);
}

// ---------------- bf16 MFMA GEMM: C = alpha * A[6144][768] @ BT[n][768]^T
// MODE 0: f32 out normal.  MODE 1: bf16 out normal (alpha).
// MODE 3: batched aw: per-batch M=N=384, mask epilogue, *alpha, NEGV fill.
// MODE 4: bf16 out TRANSPOSED per-batch (vT[b][n][l]).
template<int MODE>
__global__ __launch_bounds__(256) void k_mm(
    const ushort_t* __restrict__ A, const ushort_t* __restrict__ BT,
    float* __restrict__ Cf, ushort_t* __restrict__ Cb,
    const int* __restrict__ mask, float alpha)
{
  const int K = Dm;
  __shared__ ushort_t As[128*64];
  __shared__ ushort_t Bs[128*64];

  int bm = blockIdx.x;                  // 0..47
  int bn = blockIdx.y;                  // 0..5 (or 0..2 MODE 3)
  int m_blk = bm*128;
  int brow0 = (MODE == 3) ? ((bm/3)*Lq + bn*128) : bn*128;

  int t = threadIdx.x;
  int wave = t >> 6, lane = t & 63;
  int wr = wave >> 1, wc = wave & 1;
  int lrow = lane & 15, lkg = lane >> 4;     // 0..3

  f32x4 acc[4][4];
  #pragma unroll
  for (int i = 0; i < 4; ++i)
    #pragma unroll
    for (int j = 0; j < 4; ++j) acc[i][j] = (f32x4)(0.f);

  int sr = t >> 3, sc8 = t & 7;              // staging: row, 16B-chunk
  for (int k0 = 0; k0 < K; k0 += 64) {
    __syncthreads();
    #pragma unroll
    for (int i = 0; i < 4; ++i) {
      int row = sr + i*32;
      uint4 va = *(const uint4*)(A  + (size_t)(m_blk + row)*K + k0 + sc8*8);
      uint4 vb = *(const uint4*)(BT + (size_t)(brow0 + row)*K + k0 + sc8*8);
      int slot = sc8 ^ (row & 7);
      *(uint4*)&As[row*64 + slot*8] = va;
      *(uint4*)&Bs[row*64 + slot*8] = vb;
    }
    __syncthreads();
    #pragma unroll
    for (int kk = 0; kk < 2; ++kk) {
      bf16x8 aF[4], bF[4];
      int chunk = kk*4 + lkg;
      #pragma unroll
      for (int mi = 0; mi < 4; ++mi) {
        int arow = wr*64 + mi*16 + lrow;
        aF[mi] = *(const bf16x8*)&As[arow*64 + ((chunk ^ (arow & 7)) << 3)];
        int brow = wc*64 + mi*16 + lrow;
        bF[mi] = *(const bf16x8*)&Bs[brow*64 + ((chunk ^ (brow & 7)) << 3)];
      }
      #pragma unroll
      for (int mi = 0; mi < 4; ++mi)
        #pragma unroll
        for (int ni = 0; ni < 4; ++ni)
          acc[mi][ni] = __builtin_amdgcn_mfma_f32_16x16x32_bf16(
              aF[mi], bF[ni], acc[mi][ni], 0, 0, 0);
    }
  }

  // epilogue: C/D frag mapping col=lane&15, row=4*(lane>>4)+reg  [m89/m91]
  #pragma unroll
  for (int mi = 0; mi < 4; ++mi) {
    #pragma unroll
    for (int ni = 0; ni < 4; ++ni) {
      f32x4 a = acc[mi][ni];
      int rit = wr*64 + mi*16 + 4*lkg;        // row in tile (base of 4)
      int cit = wc*64 + ni*16 + lrow;         // col in tile
      if (MODE == 0) {
        int grow = m_blk + rit, gcol = bn*128 + cit;
        #pragma unroll
        for (int r = 0; r < 4; ++r)
          Cf[(size_t)(grow + r)*Dm + gcol] = a[r]*alpha;
      } else if (MODE == 1) {
        int grow = m_blk + rit, gcol = bn*128 + cit;
        #pragma unroll
        for (int r = 0; r < 4; ++r)
          Cb[(size_t)(grow + r)*Dm + gcol] = f2b(a[r]*alpha);
      } else if (MODE == 3) {
        int b = bm/3;
        int rl = (bm%3)*128 + rit;
        int cl = bn*128 + cit;
        const int* mb2 = mask + (size_t)b*Lq*Lq;
        float* awb = Cf + (size_t)b*Lq*Lq;
        #pragma unroll
        for (int r = 0; r < 4; ++r) {
          int m = mb2[(size_t)(rl + r)*Lq + cl];
          awb[(size_t)(rl + r)*Lq + cl] = m ? NEGV : a[r]*alpha;
        }
      } else {  // MODE 4: bf16 transposed per-batch
        int b = bm/3;
        int rl = (bm%3)*128 + rit;
        int gcol = bn*128 + cit;
        ushort4 u;
        u.x = f2b(a[0]); u.y = f2b(a[1]); u.z = f2b(a[2]); u.w = f2b(a[3]);
        *(ushort4*)&Cb[((size_t)b*Dm + gcol)*Lq + rl] = u;
      }
    }
  }
}

// ---------------- fused per-(b,h,16-q-rows) attention, MFMA QK + PV
__global__ __launch_bounds__(256) void k_attn3(
    const ushort_t* __restrict__ qbf, const ushort_t* __restrict__ kbf,
    const ushort_t* __restrict__ vT, const uint_t* __restrict__ wpair,
    const float* __restrict__ g, const float* __restrict__ rlog,
    const int* __restrict__ mask, ushort_t* __restrict__ ctxbf)
{
  __shared__ float S[QT2][400];       // logits (padded: 400%32 banks -> 2-way)
  __shared__ ushort_t Pb[QT2][392];   // combined weights bf16 (2-way)
  __shared__ float rh_s[Lq];
  __shared__ float gh_s[Lq];

  int bid = blockIdx.x;
  int h  = bid % Hn;
  int qt = (bid / Hn) % (Lq/QT2);
  int b  = bid / (Hn * (Lq/QT2));
  int q0 = qt * QT2;
  int tid = threadIdx.x, lane = tid & 63, wave = tid >> 6;
  int lrow = lane & 15, lkg = lane >> 4;
  int w4 = wave*4;

  const int* maskb = mask + (size_t)b*Lq*Lq;
  const uint_t* wpb = wpair + (size_t)b*Lq*Lq;
  const float* gh = g    + ((size_t)b*Hn + h)*Lq;
  const float* rh = rlog + ((size_t)b*Hn + h)*Lq;

  for (int e = tid; e < Lq; e += 256) { rh_s[e] = rh[e]; gh_s[e] = gh[e]; }

  // Phase 1: QK via MFMA. Wave covers k-cols [wave*96, +96).
  {
    const ushort_t* qb = qbf + ((size_t)b*Lq + q0 + lrow)*Dm + h*DH + lkg*8;
    bf16x8 aF0 = *(const bf16x8*)(qb);
    bf16x8 aF1 = *(const bf16x8*)(qb + 32);
    int col0 = wave*96;
    f32x4 acc[6];
    #pragma unroll
    for (int t = 0; t < 6; ++t) {
      int col = col0 + t*16 + lrow;
      const ushort_t* kb = kbf + ((size_t)b*Lq + col)*Dm + h*DH + lkg*8;
      bf16x8 bF0 = *(const bf16x8*)(kb);
      bf16x8 bF1 = *(const bf16x8*)(kb + 32);
      f32x4 z = (f32x4)(0.f);
      z = __builtin_amdgcn_mfma_f32_16x16x32_bf16(aF0, bF0, z, 0, 0, 0);
      z = __builtin_amdgcn_mfma_f32_16x16x32_bf16(aF1, bF1, z, 0, 0, 0);
      acc[t] = z;
    }
    #pragma unroll
    for (int t = 0; t < 6; ++t) {
      int col = col0 + t*16 + lrow;
      #pragma unroll
      for (int r = 0; r < 4; ++r) {
        int row = 4*lkg + r;
        int m = maskb[(size_t)(q0 + row)*Lq + col];
        S[row][col] = m ? NEGV : acc[t][r];
      }
    }
  }
  __syncthreads();

  // Phase 2: dual softmax + gate combine; wave owns rows w4..w4+3
  for (int r = 0; r < 4; ++r) {
    int row = w4 + r, i = q0 + row;
    float sv[6], rv[6];
    uint_t wp[6];
    float smax = -3.0e38f, rmax = -3.0e38f;
    #pragma unroll
    for (int u = 0; u < 6; ++u) {
      int kj = u*64 + lane;
      sv[u] = S[row][kj];
      wp[u] = wpb[(size_t)i*Lq + kj];
      float rel;
      if (sv[u] <= -5e17f) {
        rel = NEGV;
      } else {
        int l1 = (int)(wp[u] >> 16) - 1;
        int l2 = (int)(wp[u] & 0xFFFFu) - 1;
        rel = 0.f;
        if (l1 >= 0) rel += rh_s[l1];
        if (l2 >= 0) rel += rh_s[l2];
      }
      rv[u] = rel;
      smax = fmaxf(smax, sv[u]);
      rmax = fmaxf(rmax, rv[u]);
    }
    #pragma unroll
    for (int o = 32; o > 0; o >>= 1) {
      smax = fmaxf(smax, __shfl_xor(smax, o));
      rmax = fmaxf(rmax, __shfl_xor(rmax, o));
    }
    float ssum = 0.f, rsum = 0.f;
    #pragma unroll
    for (int u = 0; u < 6; ++u) {
      sv[u] = __expf(sv[u] - smax); ssum += sv[u];
      rv[u] = __expf(rv[u] - rmax); rsum += rv[u];
    }
    #pragma unroll
    for (int o = 32; o > 0; o >>= 1) {
      ssum += __shfl_xor(ssum, o);
      rsum += __shfl_xor(rsum, o);
    }
    float si = 1.f/ssum, ri = 1.f/rsum;
    #pragma unroll
    for (int u = 0; u < 6; ++u) {
      int kj = u*64 + lane;
      int l1 = (int)(wp[u] >> 16) - 1;
      int l2 = (int)(wp[u] & 0xFFFFu) - 1;
      float gv = 0.f;
      if (l1 >= 0) gv += gh_s[l1];
      if (l2 >= 0) gv += gh_s[l2];
      Pb[row][kj] = f2b((1.f - gv)*(sv[u]*si) + gv*(rv[u]*ri));
    }
  }
  __syncthreads();

  // Phase 3: PV via MFMA; wave covers d-slice [wave*16, +16)
  {
    int dcol = h*DH + wave*16 + lrow;
    const ushort_t* vb = vT + ((size_t)b*Dm + dcol)*Lq + lkg*8;
    f32x4 o = (f32x4)(0.f);
    #pragma unroll
    for (int ks = 0; ks < 12; ++ks) {
      bf16x8 pa = *(const bf16x8*)&Pb[lrow][ks*32 + lkg*8];
      bf16x8 bv = *(const bf16x8*)(vb + ks*32);
      o = __builtin_amdgcn_mfma_f32_16x16x32_bf16(pa, bv, o, 0, 0, 0);
    }
    #pragma unroll
    for (int r = 0; r < 4; ++r)
      ctxbf[((size_t)b*Lq + q0 + 4*lkg + r)*Dm + dcol] = f2b(o[r]);
  }
}

extern "C" void kernel_launch(void* const* d_in, const int* in_sizes, int n_in,
                              void* d_out, int out_size, void* d_ws, size_t ws_size,
                              hipStream_t stream) {
  const float* queries   = (const float*)d_in[0];
  const float* keys      = (const float*)d_in[1];
  const float* values    = (const float*)d_in[2];
  const float* relations = (const float*)d_in[3];
  const int*   dp_map    = (const int*)d_in[4];
  const int*   mask      = (const int*)d_in[5];
  const int*   rel_mask  = (const int*)d_in[6];
  const float* Wq  = (const float*)d_in[7];
  const float* Wk  = (const float*)d_in[8];
  const float* Wv  = (const float*)d_in[9];
  const float* Wo  = (const float*)d_in[10];
  const float* Wge = (const float*)d_in[11];
  const float* Wgr = (const float*)d_in[12];
  const float* Vr  = (const float*)d_in[13];
  const float* Vg  = (const float*)d_in[14];

  float* ws = (float*)d_ws;
  const size_t SZ   = (size_t)Bn*Lq*Dm;      // 4718592
  const size_t WINS = (size_t)Bn*Lq*Lq;      // 2359296
  const size_t GSZ  = (size_t)Bn*Hn*Lq;      // 73728

  int*   win  = (int*)ws;
  float* g    = ws + WINS;
  float* rlog = g + GSZ;
  float* Age  = rlog + GSZ;
  float* Agr  = Age + (size_t)Hn*Dm;
  ushort_t* Ibf = (ushort_t*)(Agr + (size_t)Hn*Dm);
  uint_t* wpair = (uint_t*)Ibf;              // alias: Ibf dead after v-GEMM
  ushort_t* qbf = Ibf + SZ;
  ushort_t* kbf = qbf + SZ;
  ushort_t* vTbf = kbf + SZ;
  ushort_t* ctxbf = vTbf + SZ;
  ushort_t* WqT = ctxbf + SZ;
  ushort_t* WkT = WqT + (size_t)Dm*Dm;
  ushort_t* WvT = WkT + (size_t)Dm*Dm;
  ushort_t* WoT = WvT + (size_t)Dm*Dm;

  float* outp = (float*)d_out;               // (B,L,D)
  float* awp  = outp + SZ;                   // (B,L,L)

  hipMemsetAsync(win, 0xFF, WINS*sizeof(int), stream);
  k_prep_age<<<2*Hn, 256, 0, stream>>>(Wge, Wgr, Vg, Age, Agr);
  k_win<<<(Bn*Lq + 255)/256, 256, 0, stream>>>(dp_map, win);
  k_grlog<<<Bn*Lq, 256, 0, stream>>>(values, relations, dp_map, rel_mask,
                                     Age, Agr, Vr, g, rlog);
  k_wT<<<dim3(Dm/32, Dm/32), 256, 0, stream>>>(Wq, WqT);
  k_wT<<<dim3(Dm/32, Dm/32), 256, 0, stream>>>(Wk, WkT);
  k_wT<<<dim3(Dm/32, Dm/32), 256, 0, stream>>>(Wv, WvT);
  k_wT<<<dim3(Dm/32, Dm/32), 256, 0, stream>>>(Wo, WoT);

  k_f2b<<<SZ/4/256, 256, 0, stream>>>(queries, Ibf);
  k_mm<1><<<dim3(48, 6), 256, 0, stream>>>(Ibf, WqT, nullptr, qbf, nullptr, 0.125f);
  k_f2b<<<SZ/4/256, 256, 0, stream>>>(keys, Ibf);
  k_mm<1><<<dim3(48, 6), 256, 0, stream>>>(Ibf, WkT, nullptr, kbf, nullptr, 1.f);
  k_f2b<<<SZ/4/256, 256, 0, stream>>>(values, Ibf);
  k_mm<4><<<dim3(48, 6), 256, 0, stream>>>(Ibf, WvT, nullptr, vTbf, nullptr, 1.f);

  k_pair<<<dim3(Lq/32, Lq/32, Bn), 256, 0, stream>>>(win, wpair);
  k_mm<3><<<dim3(48, 3), 256, 0, stream>>>(qbf, kbf, awp, nullptr, mask, 1.f/12.f);
  k_attn3<<<Bn*(Lq/QT2)*Hn, 256, 0, stream>>>(qbf, kbf, vTbf, wpair, g, rlog,
                                              mask, ctxbf);
  k_mm<0><<<dim3(48, 6), 256, 0, stream>>>(ctxbf, WoT, outp, nullptr, nullptr, 1.f);
}

// Round 5
// 245.514 us; speedup vs baseline: 7.4847x; 1.3367x over previous
//
#include <hip/hip_runtime.h>
#include <math.h>

#define Bn 16
#define Lq 384
#define Hn 12
#define Dm 768
#define DH 64
#define QT2 16
#define NEGV (-1e18f)
#define SPAD 402   // S row stride in f32: 402%32=18 -> phase-1 write rows spread {0,8,16,24}

typedef __attribute__((ext_vector_type(4))) float f32x4;
typedef __attribute__((ext_vector_type(8))) __bf16 bf16x8;
typedef __attribute__((ext_vector_type(4))) __bf16 bf16x4;
typedef unsigned short ushort_t;
typedef unsigned int uint_t;

__device__ __forceinline__ ushort_t f2b(float f) {
  unsigned int u = __float_as_uint(f);
  unsigned int r = (u + 0x7FFFu + ((u >> 16) & 1u)) >> 16;
  return (ushort_t)r;
}
__device__ __forceinline__ float b2f(ushort_t u) {
  return __uint_as_float(((unsigned int)u) << 16);
}

// ---------------- Age/Agr precompute
__global__ __launch_bounds__(256) void k_prep_age(
    const float* __restrict__ Wge, const float* __restrict__ Wgr,
    const float* __restrict__ Vg, float* __restrict__ Age, float* __restrict__ Agr)
{
  int which = blockIdx.x / Hn;
  int h = blockIdx.x % Hn;
  const float* Wsrc = which ? Wgr : Wge;
  float* dst = which ? Agr : Age;
  __shared__ float vg[DH];
  if (threadIdx.x < DH) vg[threadIdx.x] = Vg[h*DH + threadIdx.x];
  __syncthreads();
  for (int d = threadIdx.x; d < Dm; d += 256) {
    const float* wrow = Wsrc + (size_t)d*Dm + h*DH;
    float s = 0.f;
    #pragma unroll 8
    for (int j = 0; j < DH; ++j) s = fmaf(wrow[j], vg[j], s);
    dst[h*Dm + d] = s;
  }
}

// ---------------- winner map
__global__ void k_win(const int* __restrict__ dp, int* __restrict__ win) {
  int i = blockIdx.x*256 + threadIdx.x;
  if (i >= Bn*Lq) return;
  int b = i / Lq, l = i % Lq;
  int p0 = dp[(size_t)(b*2+0)*Lq + l];
  int p1 = dp[(size_t)(b*2+1)*Lq + l];
  atomicMax(&win[(size_t)b*Lq*Lq + (size_t)p0*Lq + p1], l);
}

// ---------------- pack (mask<<31 | (win[i][j]+1)<<16 | (win[j][i]+1))
__global__ __launch_bounds__(256) void k_pair(
    const int* __restrict__ win, const int* __restrict__ mask,
    uint_t* __restrict__ wpair)
{
  __shared__ int tB[32][33];
  int b = blockIdx.z;
  int i0 = blockIdx.x*32, j0 = blockIdx.y*32;
  const int* wb = win + (size_t)b*Lq*Lq;
  const int* mb = mask + (size_t)b*Lq*Lq;
  int tx = threadIdx.x & 31, ty = threadIdx.x >> 5;
  #pragma unroll
  for (int rr = 0; rr < 4; ++rr) {
    int r = ty + rr*8;
    tB[r][tx] = wb[(size_t)(j0+r)*Lq + i0 + tx];
  }
  __syncthreads();
  #pragma unroll
  for (int rr = 0; rr < 4; ++rr) {
    int ti = ty + rr*8;
    int i = i0 + ti, j = j0 + tx;
    int l1 = wb[(size_t)i*Lq + j];
    int l2 = tB[tx][ti];
    int mk = mb[(size_t)i*Lq + j];
    wpair[(size_t)b*Lq*Lq + (size_t)i*Lq + j] =
        ((uint_t)(mk != 0) << 31) | ((unsigned)(l1 + 1) << 16) | (unsigned)(l2 + 1);
  }
}

// ---------------- g (tanh gate) and rlog per (b,l)
__global__ __launch_bounds__(256) void k_grlog(
    const float* __restrict__ values, const float* __restrict__ relations,
    const int* __restrict__ dp, const int* __restrict__ rel_mask,
    const float* __restrict__ Age, const float* __restrict__ Agr,
    const float* __restrict__ Vr,
    float* __restrict__ g, float* __restrict__ rlog)
{
  int blk = blockIdx.x;
  int b = blk / Lq, l = blk % Lq;
  int tid = threadIdx.x, lane = tid & 63, wave = tid >> 6;
  __shared__ float relrow[Dm], hvrow[Dm];
  __shared__ float part[Hn][4];
  int rm = rel_mask[(size_t)b*Lq + l];
  int idx = dp[(size_t)(b*2)*Lq + l];
  const float* vrow = values + ((size_t)b*Lq + idx)*Dm;
  const float* rrow = relations + ((size_t)b*Lq + l)*Dm;
  for (int d = tid; d < Dm; d += 256) {
    relrow[d] = rm ? 0.f : rrow[d];
    hvrow[d]  = (rm || l == 0) ? 0.f : vrow[d];
  }
  __syncthreads();
  for (int h = 0; h < Hn; ++h) {
    float p = 0.f;
    for (int d = tid; d < Dm; d += 256)
      p = fmaf(hvrow[d], Age[h*Dm + d], fmaf(relrow[d], Agr[h*Dm + d], p));
    #pragma unroll
    for (int o = 32; o > 0; o >>= 1) p += __shfl_xor(p, o);
    if (lane == 0) part[h][wave] = p;
  }
  __syncthreads();
  if (tid < Hn) {
    int h = tid;
    float t = part[h][0] + part[h][1] + part[h][2] + part[h][3];
    g[((size_t)b*Hn + h)*Lq + l] = tanhf(t);
  }
  if (tid >= 64 && tid < 64 + Hn) {
    int h = tid - 64;
    float s = 0.f;
    #pragma unroll 8
    for (int j = 0; j < DH; ++j) s = fmaf(relrow[h*DH + j], Vr[h*DH + j], s);
    rlog[((size_t)b*Hn + h)*Lq + l] = s;
  }
}

// ---------------- fused f32 -> bf16 convert for q/k/v (blockIdx.y selects)
__global__ __launch_bounds__(256) void k_f2b3(
    const float* __restrict__ inq, const float* __restrict__ ink,
    const float* __restrict__ inv,
    ushort_t* __restrict__ oq, ushort_t* __restrict__ ok,
    ushort_t* __restrict__ ov)
{
  int z = blockIdx.y;
  const float* in = (z == 0) ? inq : (z == 1) ? ink : inv;
  ushort_t* out = (z == 0) ? oq : (z == 1) ? ok : ov;
  int i = blockIdx.x*256 + threadIdx.x;
  float4 f = ((const float4*)in)[i];
  ushort4 u;
  u.x = f2b(f.x); u.y = f2b(f.y); u.z = f2b(f.z); u.w = f2b(f.w);
  ((ushort4*)out)[i] = u;
}

// ---------------- all 4 weight transposes in one launch (blockIdx.z selects)
__global__ __launch_bounds__(256) void k_wT4(
    const float* __restrict__ W0, const float* __restrict__ W1,
    const float* __restrict__ W2, const float* __restrict__ W3,
    ushort_t* __restrict__ T0, ushort_t* __restrict__ T1,
    ushort_t* __restrict__ T2, ushort_t* __restrict__ T3)
{
  int z = blockIdx.z;
  const float* W = (z == 0) ? W0 : (z == 1) ? W1 : (z == 2) ? W2 : W3;
  ushort_t* WT = (z == 0) ? T0 : (z == 1) ? T1 : (z == 2) ? T2 : T3;
  __shared__ float t[32][33];
  int k0 = blockIdx.x*32, n0 = blockIdx.y*32;
  int tx = threadIdx.x & 31, ty = threadIdx.x >> 5;
  #pragma unroll
  for (int r = 0; r < 4; ++r)
    t[ty + r*8][tx] = W[(size_t)(k0 + ty + r*8)*Dm + n0 + tx];
  __syncthreads();
  #pragma unroll
  for (int r = 0; r < 4; ++r)
    WT[(size_t)(n0 + ty + r*8)*Dm + k0 + tx] = f2b(t[tx][ty + r*8]);
}

// ---------------- fused QKV projection GEMM (blockIdx.z: 0=q,1=k,2=vT)
__global__ __launch_bounds__(256) void k_mmqkv(
    const ushort_t* __restrict__ Iq, const ushort_t* __restrict__ Ik,
    const ushort_t* __restrict__ Iv,
    const ushort_t* __restrict__ WqT, const ushort_t* __restrict__ WkT,
    const ushort_t* __restrict__ WvT,
    ushort_t* __restrict__ qbf, ushort_t* __restrict__ kbf,
    ushort_t* __restrict__ vTbf)
{
  const int K = Dm;
  __shared__ ushort_t As[128*64];
  __shared__ ushort_t Bs[128*64];

  int z = blockIdx.z;
  const ushort_t* A  = (z == 0) ? Iq : (z == 1) ? Ik : Iv;
  const ushort_t* BT = (z == 0) ? WqT : (z == 1) ? WkT : WvT;

  int bm = blockIdx.x;
  int bn = blockIdx.y;
  int m_blk = bm*128;

  int t = threadIdx.x;
  int wave = t >> 6, lane = t & 63;
  int wr = wave >> 1, wc = wave & 1;
  int lrow = lane & 15, lkg = lane >> 4;

  f32x4 acc[4][4];
  #pragma unroll
  for (int i = 0; i < 4; ++i)
    #pragma unroll
    for (int j = 0; j < 4; ++j) acc[i][j] = (f32x4)(0.f);

  int sr = t >> 3, sc8 = t & 7;
  for (int k0 = 0; k0 < K; k0 += 64) {
    __syncthreads();
    #pragma unroll
    for (int i = 0; i < 4; ++i) {
      int row = sr + i*32;
      uint4 va = *(const uint4*)(A  + (size_t)(m_blk + row)*K + k0 + sc8*8);
      uint4 vb = *(const uint4*)(BT + (size_t)(bn*128 + row)*K + k0 + sc8*8);
      int slot = sc8 ^ (row & 7);
      *(uint4*)&As[row*64 + slot*8] = va;
      *(uint4*)&Bs[row*64 + slot*8] = vb;
    }
    __syncthreads();
    #pragma unroll
    for (int kk = 0; kk < 2; ++kk) {
      bf16x8 aF[4], bF[4];
      int chunk = kk*4 + lkg;
      #pragma unroll
      for (int mi = 0; mi < 4; ++mi) {
        int arow = wr*64 + mi*16 + lrow;
        aF[mi] = *(const bf16x8*)&As[arow*64 + ((chunk ^ (arow & 7)) << 3)];
        int brow = wc*64 + mi*16 + lrow;
        bF[mi] = *(const bf16x8*)&Bs[brow*64 + ((chunk ^ (brow & 7)) << 3)];
      }
      #pragma unroll
      for (int mi = 0; mi < 4; ++mi)
        #pragma unroll
        for (int ni = 0; ni < 4; ++ni)
          acc[mi][ni] = __builtin_amdgcn_mfma_f32_16x16x32_bf16(
              aF[mi], bF[ni], acc[mi][ni], 0, 0, 0);
    }
  }

  float alpha = (z == 0) ? 0.125f : 1.f;
  #pragma unroll
  for (int mi = 0; mi < 4; ++mi) {
    #pragma unroll
    for (int ni = 0; ni < 4; ++ni) {
      f32x4 a = acc[mi][ni];
      int rit = wr*64 + mi*16 + 4*lkg;
      int cit = wc*64 + ni*16 + lrow;
      int gcol = bn*128 + cit;
      if (z < 2) {
        ushort_t* Cb = z ? kbf : qbf;
        int grow = m_blk + rit;
        #pragma unroll
        for (int r = 0; r < 4; ++r)
          Cb[(size_t)(grow + r)*Dm + gcol] = f2b(a[r]*alpha);
      } else {
        int b = bm/3;
        int rl = (bm%3)*128 + rit;
        ushort4 u;
        u.x = f2b(a[0]); u.y = f2b(a[1]); u.z = f2b(a[2]); u.w = f2b(a[3]);
        *(ushort4*)&vTbf[((size_t)b*Dm + gcol)*Lq + rl] = u;
      }
    }
  }
}

// ---------------- bf16 MFMA GEMM (remaining modes)
// MODE 0: f32 out normal.  MODE 3: batched aw with mask epilogue.
template<int MODE>
__global__ __launch_bounds__(256) void k_mm(
    const ushort_t* __restrict__ A, const ushort_t* __restrict__ BT,
    float* __restrict__ Cf, ushort_t* __restrict__ Cb,
    const int* __restrict__ mask, float alpha)
{
  const int K = Dm;
  __shared__ ushort_t As[128*64];
  __shared__ ushort_t Bs[128*64];

  int bm = blockIdx.x;
  int bn = blockIdx.y;
  int m_blk = bm*128;
  int brow0 = (MODE == 3) ? ((bm/3)*Lq + bn*128) : bn*128;

  int t = threadIdx.x;
  int wave = t >> 6, lane = t & 63;
  int wr = wave >> 1, wc = wave & 1;
  int lrow = lane & 15, lkg = lane >> 4;

  f32x4 acc[4][4];
  #pragma unroll
  for (int i = 0; i < 4; ++i)
    #pragma unroll
    for (int j = 0; j < 4; ++j) acc[i][j] = (f32x4)(0.f);

  int sr = t >> 3, sc8 = t & 7;
  for (int k0 = 0; k0 < K; k0 += 64) {
    __syncthreads();
    #pragma unroll
    for (int i = 0; i < 4; ++i) {
      int row = sr + i*32;
      uint4 va = *(const uint4*)(A  + (size_t)(m_blk + row)*K + k0 + sc8*8);
      uint4 vb = *(const uint4*)(BT + (size_t)(brow0 + row)*K + k0 + sc8*8);
      int slot = sc8 ^ (row & 7);
      *(uint4*)&As[row*64 + slot*8] = va;
      *(uint4*)&Bs[row*64 + slot*8] = vb;
    }
    __syncthreads();
    #pragma unroll
    for (int kk = 0; kk < 2; ++kk) {
      bf16x8 aF[4], bF[4];
      int chunk = kk*4 + lkg;
      #pragma unroll
      for (int mi = 0; mi < 4; ++mi) {
        int arow = wr*64 + mi*16 + lrow;
        aF[mi] = *(const bf16x8*)&As[arow*64 + ((chunk ^ (arow & 7)) << 3)];
        int brow = wc*64 + mi*16 + lrow;
        bF[mi] = *(const bf16x8*)&Bs[brow*64 + ((chunk ^ (brow & 7)) << 3)];
      }
      #pragma unroll
      for (int mi = 0; mi < 4; ++mi)
        #pragma unroll
        for (int ni = 0; ni < 4; ++ni)
          acc[mi][ni] = __builtin_amdgcn_mfma_f32_16x16x32_bf16(
              aF[mi], bF[ni], acc[mi][ni], 0, 0, 0);
    }
  }

  #pragma unroll
  for (int mi = 0; mi < 4; ++mi) {
    #pragma unroll
    for (int ni = 0; ni < 4; ++ni) {
      f32x4 a = acc[mi][ni];
      int rit = wr*64 + mi*16 + 4*lkg;
      int cit = wc*64 + ni*16 + lrow;
      if (MODE == 0) {
        int grow = m_blk + rit, gcol = bn*128 + cit;
        #pragma unroll
        for (int r = 0; r < 4; ++r)
          Cf[(size_t)(grow + r)*Dm + gcol] = a[r]*alpha;
      } else {  // MODE 3
        int b = bm/3;
        int rl = (bm%3)*128 + rit;
        int cl = bn*128 + cit;
        const int* mb2 = mask + (size_t)b*Lq*Lq;
        float* awb = Cf + (size_t)b*Lq*Lq;
        #pragma unroll
        for (int r = 0; r < 4; ++r) {
          int m = mb2[(size_t)(rl + r)*Lq + cl];
          awb[(size_t)(rl + r)*Lq + cl] = m ? NEGV : a[r]*alpha;
        }
      }
    }
  }
}

// ---------------- fused per-(b,h,16-q-rows) attention, MFMA QK + PV
// LDS: S[16][402] f32 (logits), P bf16 overlaid into each S row's storage.
__global__ __launch_bounds__(256, 5) void k_attn3(
    const ushort_t* __restrict__ qbf, const ushort_t* __restrict__ kbf,
    const ushort_t* __restrict__ vT, const uint_t* __restrict__ wpair,
    const float* __restrict__ g, const float* __restrict__ rlog,
    ushort_t* __restrict__ ctxbf)
{
  __shared__ float S[QT2][SPAD];      // 25.7KB; P overlays row storage (wave-exclusive rows)
  __shared__ float rh_s[Lq];
  __shared__ float gh_s[Lq];

  int bid = blockIdx.x;
  int h  = bid % Hn;
  int qt = (bid / Hn) % (Lq/QT2);
  int b  = bid / (Hn * (Lq/QT2));
  int q0 = qt * QT2;
  int tid = threadIdx.x, lane = tid & 63, wave = tid >> 6;
  int lrow = lane & 15, lkg = lane >> 4;
  int w4 = wave*4;

  const uint_t* wpb = wpair + (size_t)b*Lq*Lq;
  const float* gh = g    + ((size_t)b*Hn + h)*Lq;
  const float* rh = rlog + ((size_t)b*Hn + h)*Lq;

  // prefetch phase-2's wpair rows into registers (latency hides under phase 1)
  uint_t wpre[4][6];
  #pragma unroll
  for (int r = 0; r < 4; ++r) {
    const uint_t* wrow = wpb + (size_t)(q0 + w4 + r)*Lq + lane;
    #pragma unroll
    for (int u = 0; u < 6; ++u) wpre[r][u] = wrow[u*64];
  }

  for (int e = tid; e < Lq; e += 256) { rh_s[e] = rh[e]; gh_s[e] = gh[e]; }

  // Phase 1: QK via MFMA (raw logits; mask applied in phase 2 from wpre bit31)
  {
    const ushort_t* qb = qbf + ((size_t)b*Lq + q0 + lrow)*Dm + h*DH + lkg*8;
    bf16x8 aF0 = *(const bf16x8*)(qb);
    bf16x8 aF1 = *(const bf16x8*)(qb + 32);
    int col0 = wave*96;
    f32x4 acc[6];
    #pragma unroll
    for (int tt = 0; tt < 6; ++tt) {
      int col = col0 + tt*16 + lrow;
      const ushort_t* kb = kbf + ((size_t)b*Lq + col)*Dm + h*DH + lkg*8;
      bf16x8 bF0 = *(const bf16x8*)(kb);
      bf16x8 bF1 = *(const bf16x8*)(kb + 32);
      f32x4 z = (f32x4)(0.f);
      z = __builtin_amdgcn_mfma_f32_16x16x32_bf16(aF0, bF0, z, 0, 0, 0);
      z = __builtin_amdgcn_mfma_f32_16x16x32_bf16(aF1, bF1, z, 0, 0, 0);
      acc[tt] = z;
    }
    #pragma unroll
    for (int tt = 0; tt < 6; ++tt) {
      int col = col0 + tt*16 + lrow;
      #pragma unroll
      for (int r = 0; r < 4; ++r)
        S[4*lkg + r][col] = acc[tt][r];
    }
  }
  __syncthreads();

  // Phase 2: dual softmax + gate combine; wave owns rows w4..w4+3
  for (int r = 0; r < 4; ++r) {
    int row = w4 + r;
    float sv[6], rv[6];
    int l1a[6], l2a[6];
    float smax = -3.0e38f, rmax = -3.0e38f;
    #pragma unroll
    for (int u = 0; u < 6; ++u) {
      int kj = u*64 + lane;
      uint_t w = wpre[r][u];
      bool msk = (w >> 31) != 0;
      int l1 = (int)((w >> 16) & 0x7FFFu) - 1;
      int l2 = (int)(w & 0xFFFFu) - 1;
      l1a[u] = l1; l2a[u] = l2;
      float s = msk ? NEGV : S[row][kj];
      float rel;
      if (msk) {
        rel = NEGV;
      } else {
        rel = 0.f;
        if (l1 >= 0) rel += rh_s[l1];
        if (l2 >= 0) rel += rh_s[l2];
      }
      sv[u] = s; rv[u] = rel;
      smax = fmaxf(smax, s);
      rmax = fmaxf(rmax, rel);
    }
    #pragma unroll
    for (int o = 32; o > 0; o >>= 1) {
      smax = fmaxf(smax, __shfl_xor(smax, o));
      rmax = fmaxf(rmax, __shfl_xor(rmax, o));
    }
    float ssum = 0.f, rsum = 0.f;
    #pragma unroll
    for (int u = 0; u < 6; ++u) {
      sv[u] = __expf(sv[u] - smax); ssum += sv[u];
      rv[u] = __expf(rv[u] - rmax); rsum += rv[u];
    }
    #pragma unroll
    for (int o = 32; o > 0; o >>= 1) {
      ssum += __shfl_xor(ssum, o);
      rsum += __shfl_xor(rsum, o);
    }
    float si = 1.f/ssum, ri = 1.f/rsum;
    ushort_t* prow = (ushort_t*)&S[row][0];
    #pragma unroll
    for (int u = 0; u < 6; ++u) {
      int kj = u*64 + lane;
      float gv = 0.f;
      if (l1a[u] >= 0) gv += gh_s[l1a[u]];
      if (l2a[u] >= 0) gv += gh_s[l2a[u]];
      prow[kj] = f2b((1.f - gv)*(sv[u]*si) + gv*(rv[u]*ri));
    }
  }
  __syncthreads();

  // Phase 3: PV via MFMA; wave covers d-slice [wave*16, +16)
  {
    int dcol = h*DH + wave*16 + lrow;
    const ushort_t* vb = vT + ((size_t)b*Dm + dcol)*Lq + lkg*8;
    const ushort_t* prow = (const ushort_t*)&S[lrow][0];
    f32x4 o = (f32x4)(0.f);
    #pragma unroll
    for (int ks = 0; ks < 12; ++ks) {
      bf16x4 lo = *(const bf16x4*)(prow + ks*32 + lkg*8);
      bf16x4 hi = *(const bf16x4*)(prow + ks*32 + lkg*8 + 4);
      bf16x8 pa = __builtin_shufflevector(lo, hi, 0,1,2,3,4,5,6,7);
      bf16x8 bv = *(const bf16x8*)(vb + ks*32);
      o = __builtin_amdgcn_mfma_f32_16x16x32_bf16(pa, bv, o, 0, 0, 0);
    }
    #pragma unroll
    for (int r = 0; r < 4; ++r)
      ctxbf[((size_t)b*Lq + q0 + 4*lkg + r)*Dm + dcol] = f2b(o[r]);
  }
}

extern "C" void kernel_launch(void* const* d_in, const int* in_sizes, int n_in,
                              void* d_out, int out_size, void* d_ws, size_t ws_size,
                              hipStream_t stream) {
  const float* queries   = (const float*)d_in[0];
  const float* keys      = (const float*)d_in[1];
  const float* values    = (const float*)d_in[2];
  const float* relations = (const float*)d_in[3];
  const int*   dp_map    = (const int*)d_in[4];
  const int*   mask      = (const int*)d_in[5];
  const int*   rel_mask  = (const int*)d_in[6];
  const float* Wq  = (const float*)d_in[7];
  const float* Wk  = (const float*)d_in[8];
  const float* Wv  = (const float*)d_in[9];
  const float* Wo  = (const float*)d_in[10];
  const float* Wge = (const float*)d_in[11];
  const float* Wgr = (const float*)d_in[12];
  const float* Vr  = (const float*)d_in[13];
  const float* Vg  = (const float*)d_in[14];

  float* ws = (float*)d_ws;
  const size_t SZ   = (size_t)Bn*Lq*Dm;      // 4718592
  const size_t WINS = (size_t)Bn*Lq*Lq;      // 2359296
  const size_t GSZ  = (size_t)Bn*Hn*Lq;      // 73728

  int*   win  = (int*)ws;
  float* g    = ws + WINS;
  float* rlog = g + GSZ;
  float* Age  = rlog + GSZ;
  float* Agr  = Age + (size_t)Hn*Dm;
  ushort_t* p0 = (ushort_t*)(Agr + (size_t)Hn*Dm);
  ushort_t* Iq   = p0;
  ushort_t* Ik   = p0 + SZ;
  ushort_t* Iv   = p0 + 2*SZ;
  ushort_t* qbf  = p0 + 3*SZ;
  ushort_t* kbf  = p0 + 4*SZ;
  ushort_t* vTbf = p0 + 5*SZ;
  ushort_t* ctxbf= p0 + 6*SZ;
  ushort_t* WqT  = p0 + 7*SZ;
  ushort_t* WkT  = WqT + (size_t)Dm*Dm;
  ushort_t* WvT  = WkT + (size_t)Dm*Dm;
  ushort_t* WoT  = WvT + (size_t)Dm*Dm;
  uint_t* wpair = (uint_t*)Iq;               // alias: Iq dead after k_mmqkv

  float* outp = (float*)d_out;               // (B,L,D)
  float* awp  = outp + SZ;                   // (B,L,L)

  hipMemsetAsync(win, 0xFF, WINS*sizeof(int), stream);
  k_prep_age<<<2*Hn, 256, 0, stream>>>(Wge, Wgr, Vg, Age, Agr);
  k_win<<<(Bn*Lq + 255)/256, 256, 0, stream>>>(dp_map, win);
  k_grlog<<<Bn*Lq, 256, 0, stream>>>(values, relations, dp_map, rel_mask,
                                     Age, Agr, Vr, g, rlog);
  k_wT4<<<dim3(Dm/32, Dm/32, 4), 256, 0, stream>>>(Wq, Wk, Wv, Wo,
                                                   WqT, WkT, WvT, WoT);
  k_f2b3<<<dim3(SZ/4/256, 3), 256, 0, stream>>>(queries, keys, values,
                                                Iq, Ik, Iv);
  k_mmqkv<<<dim3(48, 6, 3), 256, 0, stream>>>(Iq, Ik, Iv, WqT, WkT, WvT,
                                              qbf, kbf, vTbf);
  k_pair<<<dim3(Lq/32, Lq/32, Bn), 256, 0, stream>>>(win, mask, wpair);
  k_mm<3><<<dim3(48, 3), 256, 0, stream>>>(qbf, kbf, awp, nullptr, mask, 1.f/12.f);
  k_attn3<<<Bn*(Lq/QT2)*Hn, 256, 0, stream>>>(qbf, kbf, vTbf, wpair, g, rlog,
                                              ctxbf);
  k_mm<0><<<dim3(48, 6), 256, 0, stream>>>(ctxbf, WoT, outp, nullptr, nullptr, 1.f);
}

// Round 6
// 202.745 us; speedup vs baseline: 9.0636x; 1.2110x over previous
//
#include <hip/hip_runtime.h>
#include <math.h>

#define Bn 16
#define Lq 384
#define Hn 12
#define Dm 768
#define DH 64
#define QT2 16
#define NEGV (-1e18f)
#define SPAD 402   // S row stride in f32

typedef __attribute__((ext_vector_type(4))) float f32x4;
typedef __attribute__((ext_vector_type(8))) __bf16 bf16x8;
typedef __attribute__((ext_vector_type(4))) __bf16 bf16x4;
typedef unsigned short ushort_t;
typedef unsigned int uint_t;

__device__ __forceinline__ ushort_t f2b(float f) {
  unsigned int u = __float_as_uint(f);
  unsigned int r = (u + 0x7FFFu + ((u >> 16) & 1u)) >> 16;
  return (ushort_t)r;
}
__device__ __forceinline__ bf16x8 cvt8(float4 a, float4 b) {
  bf16x8 r;
  r[0] = (__bf16)a.x; r[1] = (__bf16)a.y; r[2] = (__bf16)a.z; r[3] = (__bf16)a.w;
  r[4] = (__bf16)b.x; r[5] = (__bf16)b.y; r[6] = (__bf16)b.z; r[7] = (__bf16)b.w;
  return r;
}

// ---------------- Age/Agr precompute
__global__ __launch_bounds__(256) void k_prep_age(
    const float* __restrict__ Wge, const float* __restrict__ Wgr,
    const float* __restrict__ Vg, float* __restrict__ Age, float* __restrict__ Agr)
{
  int which = blockIdx.x / Hn;
  int h = blockIdx.x % Hn;
  const float* Wsrc = which ? Wgr : Wge;
  float* dst = which ? Agr : Age;
  __shared__ float vg[DH];
  if (threadIdx.x < DH) vg[threadIdx.x] = Vg[h*DH + threadIdx.x];
  __syncthreads();
  for (int d = threadIdx.x; d < Dm; d += 256) {
    const float* wrow = Wsrc + (size_t)d*Dm + h*DH;
    float s = 0.f;
    #pragma unroll 8
    for (int j = 0; j < DH; ++j) s = fmaf(wrow[j], vg[j], s);
    dst[h*Dm + d] = s;
  }
}

// ---------------- winner map
__global__ void k_win(const int* __restrict__ dp, int* __restrict__ win) {
  int i = blockIdx.x*256 + threadIdx.x;
  if (i >= Bn*Lq) return;
  int b = i / Lq, l = i % Lq;
  int p0 = dp[(size_t)(b*2+0)*Lq + l];
  int p1 = dp[(size_t)(b*2+1)*Lq + l];
  atomicMax(&win[(size_t)b*Lq*Lq + (size_t)p0*Lq + p1], l);
}

// ---------------- pack (mask<<31 | (win[i][j]+1)<<16 | (win[j][i]+1))
__global__ __launch_bounds__(256) void k_pair(
    const int* __restrict__ win, const int* __restrict__ mask,
    uint_t* __restrict__ wpair)
{
  __shared__ int tB[32][33];
  int b = blockIdx.z;
  int i0 = blockIdx.x*32, j0 = blockIdx.y*32;
  const int* wb = win + (size_t)b*Lq*Lq;
  const int* mb = mask + (size_t)b*Lq*Lq;
  int tx = threadIdx.x & 31, ty = threadIdx.x >> 5;
  #pragma unroll
  for (int rr = 0; rr < 4; ++rr) {
    int r = ty + rr*8;
    tB[r][tx] = wb[(size_t)(j0+r)*Lq + i0 + tx];
  }
  __syncthreads();
  #pragma unroll
  for (int rr = 0; rr < 4; ++rr) {
    int ti = ty + rr*8;
    int i = i0 + ti, j = j0 + tx;
    int l1 = wb[(size_t)i*Lq + j];
    int l2 = tB[tx][ti];
    int mk = mb[(size_t)i*Lq + j];
    wpair[(size_t)b*Lq*Lq + (size_t)i*Lq + j] =
        ((uint_t)(mk != 0) << 31) | ((unsigned)(l1 + 1) << 16) | (unsigned)(l2 + 1);
  }
}

// ---------------- g (tanh gate) and rlog; 4 l-rows per block, wave per row
__global__ __launch_bounds__(256) void k_grlog(
    const float* __restrict__ values, const float* __restrict__ relations,
    const int* __restrict__ dp, const int* __restrict__ rel_mask,
    const float* __restrict__ Age, const float* __restrict__ Agr,
    const float* __restrict__ Vr,
    float* __restrict__ g, float* __restrict__ rlog)
{
  int blk = blockIdx.x;
  int b = blk / (Lq/4), l0 = (blk % (Lq/4))*4;
  int tid = threadIdx.x, lane = tid & 63, wave = tid >> 6;
  __shared__ float relrow[4][Dm], hvrow[4][Dm];
  #pragma unroll
  for (int rr = 0; rr < 4; ++rr) {
    int l = l0 + rr;
    int rm = rel_mask[(size_t)b*Lq + l];
    int idx = dp[(size_t)(b*2)*Lq + l];
    const float* vrow = values + ((size_t)b*Lq + idx)*Dm;
    const float* rrow = relations + ((size_t)b*Lq + l)*Dm;
    for (int d = tid; d < Dm; d += 256) {
      relrow[rr][d] = rm ? 0.f : rrow[d];
      hvrow[rr][d]  = (rm || l == 0) ? 0.f : vrow[d];
    }
  }
  __syncthreads();
  int l = l0 + wave;
  for (int h = 0; h < Hn; ++h) {
    float p = 0.f;
    #pragma unroll
    for (int k = 0; k < Dm/64; ++k) {
      int d = lane + 64*k;
      p = fmaf(hvrow[wave][d], Age[h*Dm + d],
          fmaf(relrow[wave][d], Agr[h*Dm + d], p));
    }
    #pragma unroll
    for (int o = 32; o > 0; o >>= 1) p += __shfl_xor(p, o);
    if (lane == 0) g[((size_t)b*Hn + h)*Lq + l] = tanhf(p);
  }
  if (lane < Hn) {
    float s = 0.f;
    #pragma unroll 8
    for (int j = 0; j < DH; ++j)
      s = fmaf(relrow[wave][lane*DH + j], Vr[lane*DH + j], s);
    rlog[((size_t)b*Hn + lane)*Lq + l] = s;
  }
}

// ---------------- all 4 weight transposes in one launch (blockIdx.z selects)
__global__ __launch_bounds__(256) void k_wT4(
    const float* __restrict__ W0, const float* __restrict__ W1,
    const float* __restrict__ W2, const float* __restrict__ W3,
    ushort_t* __restrict__ T0, ushort_t* __restrict__ T1,
    ushort_t* __restrict__ T2, ushort_t* __restrict__ T3)
{
  int z = blockIdx.z;
  const float* W = (z == 0) ? W0 : (z == 1) ? W1 : (z == 2) ? W2 : W3;
  ushort_t* WT = (z == 0) ? T0 : (z == 1) ? T1 : (z == 2) ? T2 : T3;
  __shared__ float t[32][33];
  int k0 = blockIdx.x*32, n0 = blockIdx.y*32;
  int tx = threadIdx.x & 31, ty = threadIdx.x >> 5;
  #pragma unroll
  for (int r = 0; r < 4; ++r)
    t[ty + r*8][tx] = W[(size_t)(k0 + ty + r*8)*Dm + n0 + tx];
  __syncthreads();
  #pragma unroll
  for (int r = 0; r < 4; ++r)
    WT[(size_t)(n0 + ty + r*8)*Dm + k0 + tx] = f2b(t[tx][ty + r*8]);
}

// ---------------- fused QKV projection GEMM, f32 A staged+converted in-kernel
// blockIdx.z: 0=q (x0.125), 1=k, 2=v (transposed per-batch output)
__global__ __launch_bounds__(256) void k_mmqkv(
    const float* __restrict__ Xq, const float* __restrict__ Xk,
    const float* __restrict__ Xv,
    const ushort_t* __restrict__ WqT, const ushort_t* __restrict__ WkT,
    const ushort_t* __restrict__ WvT,
    ushort_t* __restrict__ qbf, ushort_t* __restrict__ kbf,
    ushort_t* __restrict__ vTbf)
{
  const int K = Dm;
  __shared__ ushort_t As[128*64];
  __shared__ ushort_t Bs[128*64];

  int z = blockIdx.z;
  const float* A     = (z == 0) ? Xq : (z == 1) ? Xk : Xv;
  const ushort_t* BT = (z == 0) ? WqT : (z == 1) ? WkT : WvT;

  int bm = blockIdx.x;
  int bn = blockIdx.y;
  int m_blk = bm*128;

  int t = threadIdx.x;
  int wave = t >> 6, lane = t & 63;
  int wr = wave >> 1, wc = wave & 1;
  int lrow = lane & 15, lkg = lane >> 4;

  f32x4 acc[4][4];
  #pragma unroll
  for (int i = 0; i < 4; ++i)
    #pragma unroll
    for (int j = 0; j < 4; ++j) acc[i][j] = (f32x4)(0.f);

  int sr = t >> 3, sc8 = t & 7;
  for (int k0 = 0; k0 < K; k0 += 64) {
    __syncthreads();
    #pragma unroll
    for (int i = 0; i < 4; ++i) {
      int row = sr + i*32;
      const float* ap = A + (size_t)(m_blk + row)*K + k0 + sc8*8;
      float4 f0 = *(const float4*)ap;
      float4 f1 = *(const float4*)(ap + 4);
      uint4 vb = *(const uint4*)(BT + (size_t)(bn*128 + row)*K + k0 + sc8*8);
      int slot = sc8 ^ (row & 7);
      *(bf16x8*)&As[row*64 + slot*8] = cvt8(f0, f1);
      *(uint4*)&Bs[row*64 + slot*8] = vb;
    }
    __syncthreads();
    #pragma unroll
    for (int kk = 0; kk < 2; ++kk) {
      bf16x8 aF[4], bF[4];
      int chunk = kk*4 + lkg;
      #pragma unroll
      for (int mi = 0; mi < 4; ++mi) {
        int arow = wr*64 + mi*16 + lrow;
        aF[mi] = *(const bf16x8*)&As[arow*64 + ((chunk ^ (arow & 7)) << 3)];
        int brow = wc*64 + mi*16 + lrow;
        bF[mi] = *(const bf16x8*)&Bs[brow*64 + ((chunk ^ (brow & 7)) << 3)];
      }
      #pragma unroll
      for (int mi = 0; mi < 4; ++mi)
        #pragma unroll
        for (int ni = 0; ni < 4; ++ni)
          acc[mi][ni] = __builtin_amdgcn_mfma_f32_16x16x32_bf16(
              aF[mi], bF[ni], acc[mi][ni], 0, 0, 0);
    }
  }

  float alpha = (z == 0) ? 0.125f : 1.f;
  #pragma unroll
  for (int mi = 0; mi < 4; ++mi) {
    #pragma unroll
    for (int ni = 0; ni < 4; ++ni) {
      f32x4 a = acc[mi][ni];
      int rit = wr*64 + mi*16 + 4*lkg;
      int cit = wc*64 + ni*16 + lrow;
      int gcol = bn*128 + cit;
      if (z < 2) {
        ushort_t* Cb = z ? kbf : qbf;
        int grow = m_blk + rit;
        #pragma unroll
        for (int r = 0; r < 4; ++r)
          Cb[(size_t)(grow + r)*Dm + gcol] = f2b(a[r]*alpha);
      } else {
        int b = bm/3;
        int rl = (bm%3)*128 + rit;
        ushort4 u;
        u.x = f2b(a[0]); u.y = f2b(a[1]); u.z = f2b(a[2]); u.w = f2b(a[3]);
        *(ushort4*)&vTbf[((size_t)b*Dm + gcol)*Lq + rl] = u;
      }
    }
  }
}

// ---------------- 64x128-tile bf16 GEMM. MODE 0: C[M][768] f32 (grid 96,6,1).
// MODE 3: batched aw, per-batch M=N=384, mask epilogue (grid 6,3,16).
template<int MODE>
__global__ __launch_bounds__(256) void k_mm64(
    const ushort_t* __restrict__ A, const ushort_t* __restrict__ BT,
    float* __restrict__ Cf, const int* __restrict__ mask, float alpha)
{
  const int K = Dm;
  __shared__ ushort_t As[64*64];    // 8KB
  __shared__ ushort_t Bs[128*64];   // 16KB

  int bm = blockIdx.x, bn = blockIdx.y, b = blockIdx.z;
  const ushort_t* Ab = (MODE == 3) ? A  + (size_t)b*Lq*Dm : A;
  const ushort_t* Bb = (MODE == 3) ? BT + (size_t)b*Lq*Dm : BT;
  int m0 = bm*64, n0 = bn*128;

  int t = threadIdx.x;
  int wave = t >> 6, lane = t & 63;
  int wr = wave >> 1, wc = wave & 1;      // wave tile: rows 32*wr, cols 64*wc
  int lrow = lane & 15, lkg = lane >> 4;

  f32x4 acc[2][4];
  #pragma unroll
  for (int i = 0; i < 2; ++i)
    #pragma unroll
    for (int j = 0; j < 4; ++j) acc[i][j] = (f32x4)(0.f);

  int sr = t >> 3, sc8 = t & 7;
  for (int k0 = 0; k0 < K; k0 += 64) {
    __syncthreads();
    #pragma unroll
    for (int i = 0; i < 2; ++i) {
      int row = sr + i*32;
      uint4 va = *(const uint4*)(Ab + (size_t)(m0 + row)*K + k0 + sc8*8);
      int slot = sc8 ^ (row & 7);
      *(uint4*)&As[row*64 + slot*8] = va;
    }
    #pragma unroll
    for (int i = 0; i < 4; ++i) {
      int row = sr + i*32;
      uint4 vb = *(const uint4*)(Bb + (size_t)(n0 + row)*K + k0 + sc8*8);
      int slot = sc8 ^ (row & 7);
      *(uint4*)&Bs[row*64 + slot*8] = vb;
    }
    __syncthreads();
    #pragma unroll
    for (int kk = 0; kk < 2; ++kk) {
      bf16x8 aF[2], bF[4];
      int chunk = kk*4 + lkg;
      #pragma unroll
      for (int mi = 0; mi < 2; ++mi) {
        int arow = wr*32 + mi*16 + lrow;
        aF[mi] = *(const bf16x8*)&As[arow*64 + ((chunk ^ (arow & 7)) << 3)];
      }
      #pragma unroll
      for (int ni = 0; ni < 4; ++ni) {
        int brow = wc*64 + ni*16 + lrow;
        bF[ni] = *(const bf16x8*)&Bs[brow*64 + ((chunk ^ (brow & 7)) << 3)];
      }
      #pragma unroll
      for (int mi = 0; mi < 2; ++mi)
        #pragma unroll
        for (int ni = 0; ni < 4; ++ni)
          acc[mi][ni] = __builtin_amdgcn_mfma_f32_16x16x32_bf16(
              aF[mi], bF[ni], acc[mi][ni], 0, 0, 0);
    }
  }

  #pragma unroll
  for (int mi = 0; mi < 2; ++mi) {
    #pragma unroll
    for (int ni = 0; ni < 4; ++ni) {
      f32x4 a = acc[mi][ni];
      int rit = wr*32 + mi*16 + 4*lkg;
      int cit = wc*64 + ni*16 + lrow;
      if (MODE == 0) {
        int grow = m0 + rit, gcol = n0 + cit;
        #pragma unroll
        for (int r = 0; r < 4; ++r)
          Cf[(size_t)(grow + r)*Dm + gcol] = a[r]*alpha;
      } else {
        int rl = m0 + rit, cl = n0 + cit;
        const int* mb2 = mask + (size_t)b*Lq*Lq;
        float* awb = Cf + (size_t)b*Lq*Lq;
        #pragma unroll
        for (int r = 0; r < 4; ++r) {
          int m = mb2[(size_t)(rl + r)*Lq + cl];
          awb[(size_t)(rl + r)*Lq + cl] = m ? NEGV : a[r]*alpha;
        }
      }
    }
  }
}

// ---------------- fused per-(b,h,16-q-rows) attention, MFMA QK + PV
// No-max-sub softmax (logits tiny; masked -> exp underflow to 0).
__global__ __launch_bounds__(256, 5) void k_attn3(
    const ushort_t* __restrict__ qbf, const ushort_t* __restrict__ kbf,
    const ushort_t* __restrict__ vT, const uint_t* __restrict__ wpair,
    const float* __restrict__ g, const float* __restrict__ rlog,
    ushort_t* __restrict__ ctxbf)
{
  __shared__ float S[QT2][SPAD];      // 25.7KB; P (bf16) overlays row storage
  __shared__ float2 rg2[Lq + 1];      // 3.1KB: (rlog, g) with zero slot at 0

  int bid = blockIdx.x;
  int h  = bid % Hn;
  int qt = (bid / Hn) % (Lq/QT2);
  int b  = bid / (Hn * (Lq/QT2));
  int q0 = qt * QT2;
  int tid = threadIdx.x, lane = tid & 63, wave = tid >> 6;
  int lrow = lane & 15, lkg = lane >> 4;
  int w4 = wave*4;

  const uint_t* wpb = wpair + (size_t)b*Lq*Lq;
  const float* gh = g    + ((size_t)b*Hn + h)*Lq;
  const float* rh = rlog + ((size_t)b*Hn + h)*Lq;

  // prefetch phase-2's wpair rows into registers (hides under phase 1)
  uint_t wpre[4][6];
  #pragma unroll
  for (int r = 0; r < 4; ++r) {
    const uint_t* wrow = wpb + (size_t)(q0 + w4 + r)*Lq + lane;
    #pragma unroll
    for (int u = 0; u < 6; ++u) wpre[r][u] = wrow[u*64];
  }

  if (tid == 0) { rg2[0].x = 0.f; rg2[0].y = 0.f; }
  for (int e = tid; e < Lq; e += 256) {
    float2 v2; v2.x = rh[e]; v2.y = gh[e];
    rg2[e + 1] = v2;
  }

  // Phase 1: QK via MFMA (raw logits)
  {
    const ushort_t* qb = qbf + ((size_t)b*Lq + q0 + lrow)*Dm + h*DH + lkg*8;
    bf16x8 aF0 = *(const bf16x8*)(qb);
    bf16x8 aF1 = *(const bf16x8*)(qb + 32);
    int col0 = wave*96;
    f32x4 acc[6];
    #pragma unroll
    for (int tt = 0; tt < 6; ++tt) {
      int col = col0 + tt*16 + lrow;
      const ushort_t* kb = kbf + ((size_t)b*Lq + col)*Dm + h*DH + lkg*8;
      bf16x8 bF0 = *(const bf16x8*)(kb);
      bf16x8 bF1 = *(const bf16x8*)(kb + 32);
      f32x4 z = (f32x4)(0.f);
      z = __builtin_amdgcn_mfma_f32_16x16x32_bf16(aF0, bF0, z, 0, 0, 0);
      z = __builtin_amdgcn_mfma_f32_16x16x32_bf16(aF1, bF1, z, 0, 0, 0);
      acc[tt] = z;
    }
    #pragma unroll
    for (int tt = 0; tt < 6; ++tt) {
      int col = col0 + tt*16 + lrow;
      #pragma unroll
      for (int r = 0; r < 4; ++r)
        S[4*lkg + r][col] = acc[tt][r];
    }
  }
  __syncthreads();

  // Phase 2: dual softmax (no max-sub) + gate combine; wave owns 4 rows
  for (int r = 0; r < 4; ++r) {
    int row = w4 + r;
    float sv[6], rv[6], gv[6];
    #pragma unroll
    for (int u = 0; u < 6; ++u) {
      int kj = u*64 + lane;
      uint_t w = wpre[r][u];
      uint_t i1 = (w >> 16) & 0x7FFFu;
      uint_t i2 = w & 0xFFFFu;
      float2 a = rg2[i1];
      float2 c = rg2[i2];
      bool msk = (int)w < 0;
      sv[u] = msk ? NEGV : S[row][kj];
      rv[u] = msk ? NEGV : (a.x + c.x);
      gv[u] = a.y + c.y;
    }
    float ssum = 0.f, rsum = 0.f;
    #pragma unroll
    for (int u = 0; u < 6; ++u) {
      sv[u] = __expf(sv[u]); ssum += sv[u];
      rv[u] = __expf(rv[u]); rsum += rv[u];
    }
    #pragma unroll
    for (int o = 32; o > 0; o >>= 1) {
      ssum += __shfl_xor(ssum, o);
      rsum += __shfl_xor(rsum, o);
    }
    float si = 1.f/ssum, ri = 1.f/rsum;
    ushort_t* prow = (ushort_t*)&S[row][0];
    #pragma unroll
    for (int u = 0; u < 6; ++u) {
      int kj = u*64 + lane;
      float t1 = sv[u]*si;
      float p = fmaf(gv[u], fmaf(rv[u], ri, -t1), t1);
      prow[kj] = f2b(p);
    }
  }
  __syncthreads();

  // Phase 3: PV via MFMA; wave covers d-slice [wave*16, +16)
  {
    int dcol = h*DH + wave*16 + lrow;
    const ushort_t* vb = vT + ((size_t)b*Dm + dcol)*Lq + lkg*8;
    const ushort_t* prow = (const ushort_t*)&S[lrow][0];
    f32x4 o = (f32x4)(0.f);
    #pragma unroll
    for (int ks = 0; ks < 12; ++ks) {
      bf16x4 lo = *(const bf16x4*)(prow + ks*32 + lkg*8);
      bf16x4 hi = *(const bf16x4*)(prow + ks*32 + lkg*8 + 4);
      bf16x8 pa = __builtin_shufflevector(lo, hi, 0,1,2,3,4,5,6,7);
      bf16x8 bv = *(const bf16x8*)(vb + ks*32);
      o = __builtin_amdgcn_mfma_f32_16x16x32_bf16(pa, bv, o, 0, 0, 0);
    }
    #pragma unroll
    for (int r = 0; r < 4; ++r)
      ctxbf[((size_t)b*Lq + q0 + 4*lkg + r)*Dm + dcol] = f2b(o[r]);
  }
}

extern "C" void kernel_launch(void* const* d_in, const int* in_sizes, int n_in,
                              void* d_out, int out_size, void* d_ws, size_t ws_size,
                              hipStream_t stream) {
  const float* queries   = (const float*)d_in[0];
  const float* keys      = (const float*)d_in[1];
  const float* values    = (const float*)d_in[2];
  const float* relations = (const float*)d_in[3];
  const int*   dp_map    = (const int*)d_in[4];
  const int*   mask      = (const int*)d_in[5];
  const int*   rel_mask  = (const int*)d_in[6];
  const float* Wq  = (const float*)d_in[7];
  const float* Wk  = (const float*)d_in[8];
  const float* Wv  = (const float*)d_in[9];
  const float* Wo  = (const float*)d_in[10];
  const float* Wge = (const float*)d_in[11];
  const float* Wgr = (const float*)d_in[12];
  const float* Vr  = (const float*)d_in[13];
  const float* Vg  = (const float*)d_in[14];

  float* ws = (float*)d_ws;
  const size_t SZ   = (size_t)Bn*Lq*Dm;      // 4718592
  const size_t WINS = (size_t)Bn*Lq*Lq;      // 2359296
  const size_t GSZ  = (size_t)Bn*Hn*Lq;      // 73728

  int*   win  = (int*)ws;
  float* g    = ws + WINS;
  float* rlog = g + GSZ;
  float* Age  = rlog + GSZ;
  float* Agr  = Age + (size_t)Hn*Dm;
  uint_t* wpair = (uint_t*)(Agr + (size_t)Hn*Dm);
  ushort_t* p0 = (ushort_t*)(wpair + WINS);
  ushort_t* qbf  = p0;
  ushort_t* kbf  = p0 + SZ;
  ushort_t* vTbf = p0 + 2*SZ;
  ushort_t* ctxbf= p0 + 3*SZ;
  ushort_t* WqT  = p0 + 4*SZ;
  ushort_t* WkT  = WqT + (size_t)Dm*Dm;
  ushort_t* WvT  = WkT + (size_t)Dm*Dm;
  ushort_t* WoT  = WvT + (size_t)Dm*Dm;

  float* outp = (float*)d_out;               // (B,L,D)
  float* awp  = outp + SZ;                   // (B,L,L)

  hipMemsetAsync(win, 0xFF, WINS*sizeof(int), stream);
  k_prep_age<<<2*Hn, 256, 0, stream>>>(Wge, Wgr, Vg, Age, Agr);
  k_win<<<(Bn*Lq + 255)/256, 256, 0, stream>>>(dp_map, win);
  k_grlog<<<Bn*Lq/4, 256, 0, stream>>>(values, relations, dp_map, rel_mask,
                                       Age, Agr, Vr, g, rlog);
  k_wT4<<<dim3(Dm/32, Dm/32, 4), 256, 0, stream>>>(Wq, Wk, Wv, Wo,
                                                   WqT, WkT, WvT, WoT);
  k_mmqkv<<<dim3(48, 6, 3), 256, 0, stream>>>(queries, keys, values,
                                              WqT, WkT, WvT, qbf, kbf, vTbf);
  k_pair<<<dim3(Lq/32, Lq/32, Bn), 256, 0, stream>>>(win, mask, wpair);
  k_mm64<3><<<dim3(6, 3, Bn), 256, 0, stream>>>(qbf, kbf, awp, mask, 1.f/12.f);
  k_attn3<<<Bn*(Lq/QT2)*Hn, 256, 0, stream>>>(qbf, kbf, vTbf, wpair, g, rlog,
                                              ctxbf);
  k_mm64<0><<<dim3(96, 6, 1), 256, 0, stream>>>(ctxbf, WoT, outp, nullptr, 1.f);
}

// Round 7
// 197.260 us; speedup vs baseline: 9.3157x; 1.0278x over previous
//
#include <hip/hip_runtime.h>
#include <math.h>

#define Bn 16
#define Lq 384
#define Hn 12
#define Dm 768
#define DH 64
#define QT2 16
#define NEGV (-1e18f)
#define SPADU 404   // expS/P row stride in ushort: 404*2/4=202==10 mod 32 banks

typedef __attribute__((ext_vector_type(4))) float f32x4;
typedef __attribute__((ext_vector_type(8))) __bf16 bf16x8;
typedef __attribute__((ext_vector_type(4))) __bf16 bf16x4;
typedef unsigned short ushort_t;
typedef unsigned int uint_t;

__device__ __forceinline__ ushort_t f2b(float f) {
  unsigned int u = __float_as_uint(f);
  unsigned int r = (u + 0x7FFFu + ((u >> 16) & 1u)) >> 16;
  return (ushort_t)r;
}
__device__ __forceinline__ float b2f(ushort_t u) {
  return __uint_as_float(((unsigned int)u) << 16);
}
__device__ __forceinline__ bf16x8 cvt8(float4 a, float4 b) {
  bf16x8 r;
  r[0] = (__bf16)a.x; r[1] = (__bf16)a.y; r[2] = (__bf16)a.z; r[3] = (__bf16)a.w;
  r[4] = (__bf16)b.x; r[5] = (__bf16)b.y; r[6] = (__bf16)b.z; r[7] = (__bf16)b.w;
  return r;
}

// ---------------- merged prologue: Age/Agr (24) | weight transposes (2304) | win (24)
__global__ __launch_bounds__(256) void k_prep(
    const float* __restrict__ Wge, const float* __restrict__ Wgr,
    const float* __restrict__ Vg,
    float* __restrict__ Age, float* __restrict__ Agr,
    const float* __restrict__ W0, const float* __restrict__ W1,
    const float* __restrict__ W2, const float* __restrict__ W3,
    ushort_t* __restrict__ T0, ushort_t* __restrict__ T1,
    ushort_t* __restrict__ T2, ushort_t* __restrict__ T3,
    const int* __restrict__ dp, int* __restrict__ win)
{
  __shared__ float vg[DH];
  __shared__ float t[32][33];
  int blk = blockIdx.x;
  if (blk < 24) {
    int which = blk / Hn;
    int h = blk % Hn;
    const float* Wsrc = which ? Wgr : Wge;
    float* dst = which ? Agr : Age;
    if (threadIdx.x < DH) vg[threadIdx.x] = Vg[h*DH + threadIdx.x];
    __syncthreads();
    for (int d = threadIdx.x; d < Dm; d += 256) {
      const float* wrow = Wsrc + (size_t)d*Dm + h*DH;
      float s = 0.f;
      #pragma unroll 8
      for (int j = 0; j < DH; ++j) s = fmaf(wrow[j], vg[j], s);
      dst[h*Dm + d] = s;
    }
  } else if (blk < 24 + 2304) {
    int b2 = blk - 24;
    int z = b2 / 576, rem = b2 % 576;
    const float* W = (z == 0) ? W0 : (z == 1) ? W1 : (z == 2) ? W2 : W3;
    ushort_t* WT = (z == 0) ? T0 : (z == 1) ? T1 : (z == 2) ? T2 : T3;
    int k0 = (rem / 24)*32, n0 = (rem % 24)*32;
    int tx = threadIdx.x & 31, ty = threadIdx.x >> 5;
    #pragma unroll
    for (int r = 0; r < 4; ++r)
      t[ty + r*8][tx] = W[(size_t)(k0 + ty + r*8)*Dm + n0 + tx];
    __syncthreads();
    #pragma unroll
    for (int r = 0; r < 4; ++r)
      WT[(size_t)(n0 + ty + r*8)*Dm + k0 + tx] = f2b(t[tx][ty + r*8]);
  } else {
    int i = (blk - 2328)*256 + threadIdx.x;
    int b = i / Lq, l = i % Lq;
    int p0 = dp[(size_t)(b*2+0)*Lq + l];
    int p1 = dp[(size_t)(b*2+1)*Lq + l];
    atomicMax(&win[(size_t)b*Lq*Lq + (size_t)p0*Lq + p1], l);
  }
}

// ---------------- pack (mask<<31 | (win[i][j]+1)<<16 | (win[j][i]+1))
__global__ __launch_bounds__(256) void k_pair(
    const int* __restrict__ win, const int* __restrict__ mask,
    uint_t* __restrict__ wpair)
{
  __shared__ int tB[32][33];
  int b = blockIdx.z;
  int i0 = blockIdx.x*32, j0 = blockIdx.y*32;
  const int* wb = win + (size_t)b*Lq*Lq;
  const int* mb = mask + (size_t)b*Lq*Lq;
  int tx = threadIdx.x & 31, ty = threadIdx.x >> 5;
  #pragma unroll
  for (int rr = 0; rr < 4; ++rr) {
    int r = ty + rr*8;
    tB[r][tx] = wb[(size_t)(j0+r)*Lq + i0 + tx];
  }
  __syncthreads();
  #pragma unroll
  for (int rr = 0; rr < 4; ++rr) {
    int ti = ty + rr*8;
    int i = i0 + ti, j = j0 + tx;
    int l1 = wb[(size_t)i*Lq + j];
    int l2 = tB[tx][ti];
    int mk = mb[(size_t)i*Lq + j];
    wpair[(size_t)b*Lq*Lq + (size_t)i*Lq + j] =
        ((uint_t)(mk != 0) << 31) | ((unsigned)(l1 + 1) << 16) | (unsigned)(l2 + 1);
  }
}

// ---------------- g (tanh gate) and rlog; 4 l-rows per block, wave per row
__global__ __launch_bounds__(256) void k_grlog(
    const float* __restrict__ values, const float* __restrict__ relations,
    const int* __restrict__ dp, const int* __restrict__ rel_mask,
    const float* __restrict__ Age, const float* __restrict__ Agr,
    const float* __restrict__ Vr,
    float* __restrict__ g, float* __restrict__ rlog)
{
  int blk = blockIdx.x;
  int b = blk / (Lq/4), l0 = (blk % (Lq/4))*4;
  int tid = threadIdx.x, lane = tid & 63, wave = tid >> 6;
  __shared__ float relrow[4][Dm], hvrow[4][Dm];
  #pragma unroll
  for (int rr = 0; rr < 4; ++rr) {
    int l = l0 + rr;
    int rm = rel_mask[(size_t)b*Lq + l];
    int idx = dp[(size_t)(b*2)*Lq + l];
    const float* vrow = values + ((size_t)b*Lq + idx)*Dm;
    const float* rrow = relations + ((size_t)b*Lq + l)*Dm;
    for (int d = tid; d < Dm; d += 256) {
      relrow[rr][d] = rm ? 0.f : rrow[d];
      hvrow[rr][d]  = (rm || l == 0) ? 0.f : vrow[d];
    }
  }
  __syncthreads();
  int l = l0 + wave;
  for (int h = 0; h < Hn; ++h) {
    float p = 0.f;
    #pragma unroll
    for (int k = 0; k < Dm/64; ++k) {
      int d = lane + 64*k;
      p = fmaf(hvrow[wave][d], Age[h*Dm + d],
          fmaf(relrow[wave][d], Agr[h*Dm + d], p));
    }
    #pragma unroll
    for (int o = 32; o > 0; o >>= 1) p += __shfl_xor(p, o);
    if (lane == 0) g[((size_t)b*Hn + h)*Lq + l] = tanhf(p);
  }
  if (lane < Hn) {
    float s = 0.f;
    #pragma unroll 8
    for (int j = 0; j < DH; ++j)
      s = fmaf(relrow[wave][lane*DH + j], Vr[lane*DH + j], s);
    rlog[((size_t)b*Hn + lane)*Lq + l] = s;
  }
}

// ---------------- fused QKV projection GEMM, f32 A staged+converted in-kernel
// blockIdx.z: 0=q (x0.125), 1=k, 2=v (transposed per-batch output)
__global__ __launch_bounds__(256) void k_mmqkv(
    const float* __restrict__ Xq, const float* __restrict__ Xk,
    const float* __restrict__ Xv,
    const ushort_t* __restrict__ WqT, const ushort_t* __restrict__ WkT,
    const ushort_t* __restrict__ WvT,
    ushort_t* __restrict__ qbf, ushort_t* __restrict__ kbf,
    ushort_t* __restrict__ vTbf)
{
  const int K = Dm;
  __shared__ ushort_t As[128*64];
  __shared__ ushort_t Bs[128*64];

  int z = blockIdx.z;
  const float* A     = (z == 0) ? Xq : (z == 1) ? Xk : Xv;
  const ushort_t* BT = (z == 0) ? WqT : (z == 1) ? WkT : WvT;

  int bm = blockIdx.x;
  int bn = blockIdx.y;
  int m_blk = bm*128;

  int t = threadIdx.x;
  int wave = t >> 6, lane = t & 63;
  int wr = wave >> 1, wc = wave & 1;
  int lrow = lane & 15, lkg = lane >> 4;

  f32x4 acc[4][4];
  #pragma unroll
  for (int i = 0; i < 4; ++i)
    #pragma unroll
    for (int j = 0; j < 4; ++j) acc[i][j] = (f32x4)(0.f);

  int sr = t >> 3, sc8 = t & 7;
  for (int k0 = 0; k0 < K; k0 += 64) {
    __syncthreads();
    #pragma unroll
    for (int i = 0; i < 4; ++i) {
      int row = sr + i*32;
      const float* ap = A + (size_t)(m_blk + row)*K + k0 + sc8*8;
      float4 f0 = *(const float4*)ap;
      float4 f1 = *(const float4*)(ap + 4);
      uint4 vb = *(const uint4*)(BT + (size_t)(bn*128 + row)*K + k0 + sc8*8);
      int slot = sc8 ^ (row & 7);
      *(bf16x8*)&As[row*64 + slot*8] = cvt8(f0, f1);
      *(uint4*)&Bs[row*64 + slot*8] = vb;
    }
    __syncthreads();
    #pragma unroll
    for (int kk = 0; kk < 2; ++kk) {
      bf16x8 aF[4], bF[4];
      int chunk = kk*4 + lkg;
      #pragma unroll
      for (int mi = 0; mi < 4; ++mi) {
        int arow = wr*64 + mi*16 + lrow;
        aF[mi] = *(const bf16x8*)&As[arow*64 + ((chunk ^ (arow & 7)) << 3)];
        int brow = wc*64 + mi*16 + lrow;
        bF[mi] = *(const bf16x8*)&Bs[brow*64 + ((chunk ^ (brow & 7)) << 3)];
      }
      #pragma unroll
      for (int mi = 0; mi < 4; ++mi)
        #pragma unroll
        for (int ni = 0; ni < 4; ++ni)
          acc[mi][ni] = __builtin_amdgcn_mfma_f32_16x16x32_bf16(
              aF[mi], bF[ni], acc[mi][ni], 0, 0, 0);
    }
  }

  float alpha = (z == 0) ? 0.125f : 1.f;
  #pragma unroll
  for (int mi = 0; mi < 4; ++mi) {
    #pragma unroll
    for (int ni = 0; ni < 4; ++ni) {
      f32x4 a = acc[mi][ni];
      int rit = wr*64 + mi*16 + 4*lkg;
      int cit = wc*64 + ni*16 + lrow;
      int gcol = bn*128 + cit;
      if (z < 2) {
        ushort_t* Cb = z ? kbf : qbf;
        int grow = m_blk + rit;
        #pragma unroll
        for (int r = 0; r < 4; ++r)
          Cb[(size_t)(grow + r)*Dm + gcol] = f2b(a[r]*alpha);
      } else {
        int b = bm/3;
        int rl = (bm%3)*128 + rit;
        ushort4 u;
        u.x = f2b(a[0]); u.y = f2b(a[1]); u.z = f2b(a[2]); u.w = f2b(a[3]);
        *(ushort4*)&vTbf[((size_t)b*Dm + gcol)*Lq + rl] = u;
      }
    }
  }
}

// ---------------- 64x128-tile bf16 GEMM. MODE 0: C[M][768] f32 (grid 96,6,1).
// MODE 3: batched aw, per-batch M=N=384, mask epilogue (grid 6,3,16).
template<int MODE>
__global__ __launch_bounds__(256) void k_mm64(
    const ushort_t* __restrict__ A, const ushort_t* __restrict__ BT,
    float* __restrict__ Cf, const int* __restrict__ mask, float alpha)
{
  const int K = Dm;
  __shared__ ushort_t As[64*64];    // 8KB
  __shared__ ushort_t Bs[128*64];   // 16KB

  int bm = blockIdx.x, bn = blockIdx.y, b = blockIdx.z;
  const ushort_t* Ab = (MODE == 3) ? A  + (size_t)b*Lq*Dm : A;
  const ushort_t* Bb = (MODE == 3) ? BT + (size_t)b*Lq*Dm : BT;
  int m0 = bm*64, n0 = bn*128;

  int t = threadIdx.x;
  int wave = t >> 6, lane = t & 63;
  int wr = wave >> 1, wc = wave & 1;      // wave tile: rows 32*wr, cols 64*wc
  int lrow = lane & 15, lkg = lane >> 4;

  f32x4 acc[2][4];
  #pragma unroll
  for (int i = 0; i < 2; ++i)
    #pragma unroll
    for (int j = 0; j < 4; ++j) acc[i][j] = (f32x4)(0.f);

  int sr = t >> 3, sc8 = t & 7;
  for (int k0 = 0; k0 < K; k0 += 64) {
    __syncthreads();
    #pragma unroll
    for (int i = 0; i < 2; ++i) {
      int row = sr + i*32;
      uint4 va = *(const uint4*)(Ab + (size_t)(m0 + row)*K + k0 + sc8*8);
      int slot = sc8 ^ (row & 7);
      *(uint4*)&As[row*64 + slot*8] = va;
    }
    #pragma unroll
    for (int i = 0; i < 4; ++i) {
      int row = sr + i*32;
      uint4 vb = *(const uint4*)(Bb + (size_t)(n0 + row)*K + k0 + sc8*8);
      int slot = sc8 ^ (row & 7);
      *(uint4*)&Bs[row*64 + slot*8] = vb;
    }
    __syncthreads();
    #pragma unroll
    for (int kk = 0; kk < 2; ++kk) {
      bf16x8 aF[2], bF[4];
      int chunk = kk*4 + lkg;
      #pragma unroll
      for (int mi = 0; mi < 2; ++mi) {
        int arow = wr*32 + mi*16 + lrow;
        aF[mi] = *(const bf16x8*)&As[arow*64 + ((chunk ^ (arow & 7)) << 3)];
      }
      #pragma unroll
      for (int ni = 0; ni < 4; ++ni) {
        int brow = wc*64 + ni*16 + lrow;
        bF[ni] = *(const bf16x8*)&Bs[brow*64 + ((chunk ^ (brow & 7)) << 3)];
      }
      #pragma unroll
      for (int mi = 0; mi < 2; ++mi)
        #pragma unroll
        for (int ni = 0; ni < 4; ++ni)
          acc[mi][ni] = __builtin_amdgcn_mfma_f32_16x16x32_bf16(
              aF[mi], bF[ni], acc[mi][ni], 0, 0, 0);
    }
  }

  #pragma unroll
  for (int mi = 0; mi < 2; ++mi) {
    #pragma unroll
    for (int ni = 0; ni < 4; ++ni) {
      f32x4 a = acc[mi][ni];
      int rit = wr*32 + mi*16 + 4*lkg;
      int cit = wc*64 + ni*16 + lrow;
      if (MODE == 0) {
        int grow = m0 + rit, gcol = n0 + cit;
        #pragma unroll
        for (int r = 0; r < 4; ++r)
          Cf[(size_t)(grow + r)*Dm + gcol] = a[r]*alpha;
      } else {
        int rl = m0 + rit, cl = n0 + cit;
        const int* mb2 = mask + (size_t)b*Lq*Lq;
        float* awb = Cf + (size_t)b*Lq*Lq;
        #pragma unroll
        for (int r = 0; r < 4; ++r) {
          int m = mb2[(size_t)(rl + r)*Lq + cl];
          awb[(size_t)(rl + r)*Lq + cl] = m ? NEGV : a[r]*alpha;
        }
      }
    }
  }
}

// ---------------- fused per-(b,h,16-q-rows) attention, MFMA QK + PV
// expS stored bf16 (exp in phase 1, overlaps MFMA pipe); P overlays rows.
__global__ __launch_bounds__(256, 8) void k_attn3(
    const ushort_t* __restrict__ qbf, const ushort_t* __restrict__ kbf,
    const ushort_t* __restrict__ vT, const uint_t* __restrict__ wpair,
    const float* __restrict__ g, const float* __restrict__ rlog,
    ushort_t* __restrict__ ctxbf)
{
  __shared__ ushort_t S16[QT2][SPADU];  // 12.9KB: exp(logits) bf16, then P bf16
  __shared__ float2 rg2[Lq + 1];        // 3.1KB: (rlog, g), zero slot at 0

  int bid = blockIdx.x;
  int h  = bid % Hn;
  int qt = (bid / Hn) % (Lq/QT2);
  int b  = bid / (Hn * (Lq/QT2));
  int q0 = qt * QT2;
  int tid = threadIdx.x, lane = tid & 63, wave = tid >> 6;
  int lrow = lane & 15, lkg = lane >> 4;
  int w4 = wave*4;

  const uint_t* wpb = wpair + (size_t)b*Lq*Lq;
  const float* gh = g    + ((size_t)b*Hn + h)*Lq;
  const float* rh = rlog + ((size_t)b*Hn + h)*Lq;

  // prefetch phase-2's wpair rows into registers (hides under phase 1)
  uint_t wpre[4][6];
  #pragma unroll
  for (int r = 0; r < 4; ++r) {
    const uint_t* wrow = wpb + (size_t)(q0 + w4 + r)*Lq + lane;
    #pragma unroll
    for (int u = 0; u < 6; ++u) wpre[r][u] = wrow[u*64];
  }

  if (tid == 0) { rg2[0].x = 0.f; rg2[0].y = 0.f; }
  for (int e = tid; e < Lq; e += 256) {
    float2 v2; v2.x = rh[e]; v2.y = gh[e];
    rg2[e + 1] = v2;
  }

  // Phase 1: QK via MFMA, exp applied immediately, bf16 store
  {
    const ushort_t* qb = qbf + ((size_t)b*Lq + q0 + lrow)*Dm + h*DH + lkg*8;
    bf16x8 aF0 = *(const bf16x8*)(qb);
    bf16x8 aF1 = *(const bf16x8*)(qb + 32);
    int col0 = wave*96;
    #pragma unroll
    for (int tt = 0; tt < 6; ++tt) {
      int col = col0 + tt*16 + lrow;
      const ushort_t* kb = kbf + ((size_t)b*Lq + col)*Dm + h*DH + lkg*8;
      bf16x8 bF0 = *(const bf16x8*)(kb);
      bf16x8 bF1 = *(const bf16x8*)(kb + 32);
      f32x4 z = (f32x4)(0.f);
      z = __builtin_amdgcn_mfma_f32_16x16x32_bf16(aF0, bF0, z, 0, 0, 0);
      z = __builtin_amdgcn_mfma_f32_16x16x32_bf16(aF1, bF1, z, 0, 0, 0);
      #pragma unroll
      for (int r = 0; r < 4; ++r)
        S16[4*lkg + r][col] = f2b(__expf(z[r]));
    }
  }
  __syncthreads();

  // Phase 2: dual softmax (no max-sub; masked -> 0) + gate combine
  for (int r = 0; r < 4; ++r) {
    int row = w4 + r;
    float sv[6], rv[6], gv[6];
    float ssum = 0.f, rsum = 0.f;
    #pragma unroll
    for (int u = 0; u < 6; ++u) {
      int kj = u*64 + lane;
      uint_t w = wpre[r][u];
      uint_t i1 = (w >> 16) & 0x7FFFu;
      uint_t i2 = w & 0xFFFFu;
      float2 a = rg2[i1];
      float2 c = rg2[i2];
      bool msk = (int)w < 0;
      sv[u] = msk ? 0.f : b2f(S16[row][kj]);
      rv[u] = msk ? 0.f : __expf(a.x + c.x);
      gv[u] = a.y + c.y;
      ssum += sv[u]; rsum += rv[u];
    }
    #pragma unroll
    for (int o = 32; o > 0; o >>= 1) {
      ssum += __shfl_xor(ssum, o);
      rsum += __shfl_xor(rsum, o);
    }
    float si = 1.f/ssum, ri = 1.f/rsum;
    ushort_t* prow = &S16[row][0];
    #pragma unroll
    for (int u = 0; u < 6; ++u) {
      int kj = u*64 + lane;
      float t1 = sv[u]*si;
      float p = fmaf(gv[u], fmaf(rv[u], ri, -t1), t1);
      prow[kj] = f2b(p);
    }
  }
  __syncthreads();

  // Phase 3: PV via MFMA; wave covers d-slice [wave*16, +16)
  {
    int dcol = h*DH + wave*16 + lrow;
    const ushort_t* vb = vT + ((size_t)b*Dm + dcol)*Lq + lkg*8;
    const ushort_t* prow = &S16[lrow][0];
    f32x4 o = (f32x4)(0.f);
    #pragma unroll
    for (int ks = 0; ks < 12; ++ks) {
      bf16x4 lo = *(const bf16x4*)(prow + ks*32 + lkg*8);
      bf16x4 hi = *(const bf16x4*)(prow + ks*32 + lkg*8 + 4);
      bf16x8 pa = __builtin_shufflevector(lo, hi, 0,1,2,3,4,5,6,7);
      bf16x8 bv = *(const bf16x8*)(vb + ks*32);
      o = __builtin_amdgcn_mfma_f32_16x16x32_bf16(pa, bv, o, 0, 0, 0);
    }
    #pragma unroll
    for (int r = 0; r < 4; ++r)
      ctxbf[((size_t)b*Lq + q0 + 4*lkg + r)*Dm + dcol] = f2b(o[r]);
  }
}

extern "C" void kernel_launch(void* const* d_in, const int* in_sizes, int n_in,
                              void* d_out, int out_size, void* d_ws, size_t ws_size,
                              hipStream_t stream) {
  const float* queries   = (const float*)d_in[0];
  const float* keys      = (const float*)d_in[1];
  const float* values    = (const float*)d_in[2];
  const float* relations = (const float*)d_in[3];
  const int*   dp_map    = (const int*)d_in[4];
  const int*   mask      = (const int*)d_in[5];
  const int*   rel_mask  = (const int*)d_in[6];
  const float* Wq  = (const float*)d_in[7];
  const float* Wk  = (const float*)d_in[8];
  const float* Wv  = (const float*)d_in[9];
  const float* Wo  = (const float*)d_in[10];
  const float* Wge = (const float*)d_in[11];
  const float* Wgr = (const float*)d_in[12];
  const float* Vr  = (const float*)d_in[13];
  const float* Vg  = (const float*)d_in[14];

  float* ws = (float*)d_ws;
  const size_t SZ   = (size_t)Bn*Lq*Dm;      // 4718592
  const size_t WINS = (size_t)Bn*Lq*Lq;      // 2359296
  const size_t GSZ  = (size_t)Bn*Hn*Lq;      // 73728

  int*   win  = (int*)ws;
  float* g    = ws + WINS;
  float* rlog = g + GSZ;
  float* Age  = rlog + GSZ;
  float* Agr  = Age + (size_t)Hn*Dm;
  uint_t* wpair = (uint_t*)(Agr + (size_t)Hn*Dm);
  ushort_t* p0 = (ushort_t*)(wpair + WINS);
  ushort_t* qbf  = p0;
  ushort_t* kbf  = p0 + SZ;
  ushort_t* vTbf = p0 + 2*SZ;
  ushort_t* ctxbf= p0 + 3*SZ;
  ushort_t* WqT  = p0 + 4*SZ;
  ushort_t* WkT  = WqT + (size_t)Dm*Dm;
  ushort_t* WvT  = WkT + (size_t)Dm*Dm;
  ushort_t* WoT  = WvT + (size_t)Dm*Dm;

  float* outp = (float*)d_out;               // (B,L,D)
  float* awp  = outp + SZ;                   // (B,L,L)

  hipMemsetAsync(win, 0xFF, WINS*sizeof(int), stream);
  k_prep<<<2352, 256, 0, stream>>>(Wge, Wgr, Vg, Age, Agr,
                                   Wq, Wk, Wv, Wo, WqT, WkT, WvT, WoT,
                                   dp_map, win);
  k_grlog<<<Bn*Lq/4, 256, 0, stream>>>(values, relations, dp_map, rel_mask,
                                       Age, Agr, Vr, g, rlog);
  k_mmqkv<<<dim3(48, 6, 3), 256, 0, stream>>>(queries, keys, values,
                                              WqT, WkT, WvT, qbf, kbf, vTbf);
  k_pair<<<dim3(Lq/32, Lq/32, Bn), 256, 0, stream>>>(win, mask, wpair);
  k_mm64<3><<<dim3(6, 3, Bn), 256, 0, stream>>>(qbf, kbf, awp, mask, 1.f/12.f);
  k_attn3<<<Bn*(Lq/QT2)*Hn, 256, 0, stream>>>(qbf, kbf, vTbf, wpair, g, rlog,
                                              ctxbf);
  k_mm64<0><<<dim3(96, 6, 1), 256, 0, stream>>>(ctxbf, WoT, outp, nullptr, 1.f);
}